// Round 15
// baseline (455.991 us; speedup 1.0000x reference)
//
#include <hip/hip_runtime.h>

// B=16384, FEAT=1024, FD=256, M=4 nodes, H1=4x128 (concat->512), H2=1x256, OUT=8.
// Round 15: traffic diet. Weights preconverted fp16 (r6-validated), BN=256
// tiles (2x FLOP per staged byte, no A duplication), r12 single-ahead
// double-buffered schedule. Mid-section 2-chunked (r6-validated) to fit wf16.
// Attn kernels r14 verbatim. Math bit-identical throughout.

typedef __attribute__((ext_vector_type(8))) _Float16 f16x8;
typedef __attribute__((ext_vector_type(4))) float f32x4;
typedef _Float16 half_t;

struct P4 { const void* p[4]; };
struct P8 { const void* p[8]; };

#define SYM(i,j) ((i)*(7-(i))/2 + (j))

__device__ __forceinline__ float sigmoidf_(float x) { return 1.0f / (1.0f + __expf(-x)); }
__device__ __forceinline__ float gelu_(float x) {
    return 0.5f * x * (1.0f + erff(x * 0.70710678118654752440f));
}

// ------------- weights fp32 -> fp16 (round-6 verbatim) -----------------------
__device__ const int g_seg_n4[7]   = {65536,65536,65536,65536,32768,32768,16384};
__device__ const int g_seg_dofs[7] = {0,262144,524288,786432,1048576,1179648,1310720};

__global__ __launch_bounds__(256)
void cvt_weights(P8 srcs, half_t* __restrict__ dst)
{
    const int seg = blockIdx.y;
    const float* s = (const float*)srcs.p[seg];
    half_t* d = dst + g_seg_dofs[seg];
    const int n4 = g_seg_n4[seg];
    for (int i = blockIdx.x * 256 + threadIdx.x; i < n4; i += gridDim.x * 256) {
        const float4 v = ((const float4*)s)[i];
        union { half_t h[4]; uint2 u; } o;
        o.h[0] = (half_t)v.x; o.h[1] = (half_t)v.y;
        o.h[2] = (half_t)v.z; o.h[3] = (half_t)v.w;
        *(uint2*)(d + (size_t)i * 4) = o.u;
    }
}

// ---- MFMA NT GEMM: C[M,N] f32 = act(A[M,K] f32 @ W[N,K]^T fp16 + bias) ------
// BM=128, BN templated, BK=32, 256 threads = 4 waves (2 x 2), wave tile
// 64 x (BN/2). Double-buffered LDS, single-ahead prefetch, one barrier/iter.
template<int BN, int ACT, bool HAS_BIAS>
__global__ __launch_bounds__(256)
void gemm_bf(P4 A4, const half_t* __restrict__ Wbase, int zWofs, P4 b4,
             float* __restrict__ C, int K, int lda, int ldc, int zofs)
{
    constexpr int NB  = BN / 32;   // B fragments (and acc cols) per wave
    constexpr int NBS = BN / 64;   // B staging uint4 per thread
    __shared__ __align__(16) half_t As[2][128][32];
    __shared__ __align__(16) half_t Bs[2][BN][32];

    const int z = blockIdx.z;
    const float*  __restrict__ A    = (const float*)A4.p[z];
    const half_t* __restrict__ Wh   = Wbase + (long)z * zWofs;
    const float*  __restrict__ bias = (const float*)b4.p[z];
    float* __restrict__ Cz = C + (long)z * zofs;

    const int t    = threadIdx.x;
    const int lane = t & 63;
    const int w    = t >> 6;
    const int wr   = (w >> 1) << 6;
    const int wc   = (w & 1) * (BN / 2);
    const long rowA = (long)blockIdx.y * 128;
    const long colB = (long)blockIdx.x * BN;

    // A staging: slot f = t + i*256 -> row f>>3 (0..127), col (f&7)*4
    const float* Apt[4];
    int ar_[4], ac_[4];
    #pragma unroll
    for (int i = 0; i < 4; ++i) {
        const int f = t + i * 256;
        ar_[i] = f >> 3;
        ac_[i] = (f & 7) << 2;
        Apt[i] = A + (rowA + ar_[i]) * (long)lda + ac_[i];
    }
    // B staging: slot s = t + i*256 -> row s>>2 (0..BN-1), col (s&3)*8
    const half_t* Bpt[NBS];
    int br_[NBS], bc_[NBS];
    #pragma unroll
    for (int i = 0; i < NBS; ++i) {
        const int s = t + i * 256;
        br_[i] = s >> 2;
        bc_[i] = (s & 3) << 3;
        Bpt[i] = Wh + (colB + br_[i]) * (long)K + bc_[i];
    }

    f32x4 acc[4][NB] = {};
    const int NK = K >> 5;

    // prologue: tile 0 -> regs -> buf0
    float4 aR[4];
    uint4  bR[NBS];
    #pragma unroll
    for (int i = 0; i < 4; ++i)   aR[i] = *(const float4*)(Apt[i]);
    #pragma unroll
    for (int i = 0; i < NBS; ++i) bR[i] = *(const uint4*)(Bpt[i]);
    #pragma unroll
    for (int i = 0; i < 4; ++i) {
        union { half_t h[4]; uint2 u; } pa;
        pa.h[0] = (half_t)aR[i].x; pa.h[1] = (half_t)aR[i].y;
        pa.h[2] = (half_t)aR[i].z; pa.h[3] = (half_t)aR[i].w;
        *(uint2*)&As[0][ar_[i]][ac_[i]] = pa.u;
    }
    #pragma unroll
    for (int i = 0; i < NBS; ++i)
        *(uint4*)&Bs[0][br_[i]][bc_[i]] = bR[i];
    __syncthreads();

    const int fr = lane & 15;
    const int fg = (lane >> 4) << 3;
    int cur = 0;

    for (int kk = 0; kk < NK; ++kk) {
        const int kn = (kk + 1) << 5;
        // issue next tile's loads (hide under MFMA)
        if (kn < K) {
            #pragma unroll
            for (int i = 0; i < 4; ++i)   aR[i] = *(const float4*)(Apt[i] + kn);
            #pragma unroll
            for (int i = 0; i < NBS; ++i) bR[i] = *(const uint4*)(Bpt[i] + kn);
        }

        // fragments + MFMA on buf[cur]
        f16x8 af[4], bf[NB];
        #pragma unroll
        for (int m = 0; m < 4; ++m)  af[m] = *(const f16x8*)&As[cur][wr + m*16 + fr][fg];
        #pragma unroll
        for (int n = 0; n < NB; ++n) bf[n] = *(const f16x8*)&Bs[cur][wc + n*16 + fr][fg];
        #pragma unroll
        for (int m = 0; m < 4; ++m)
            #pragma unroll
            for (int n = 0; n < NB; ++n)
                acc[m][n] = __builtin_amdgcn_mfma_f32_16x16x32_f16(af[m], bf[n], acc[m][n], 0, 0, 0);

        // store next tile into other buffer
        if (kn < K) {
            const int nxt = cur ^ 1;
            #pragma unroll
            for (int i = 0; i < 4; ++i) {
                union { half_t h[4]; uint2 u; } pa;
                pa.h[0] = (half_t)aR[i].x; pa.h[1] = (half_t)aR[i].y;
                pa.h[2] = (half_t)aR[i].z; pa.h[3] = (half_t)aR[i].w;
                *(uint2*)&As[nxt][ar_[i]][ac_[i]] = pa.u;
            }
            #pragma unroll
            for (int i = 0; i < NBS; ++i)
                *(uint4*)&Bs[nxt][br_[i]][bc_[i]] = bR[i];
        }
        __syncthreads();
        cur ^= 1;
    }

    // epilogue: col = lane&15, row = (lane>>4)*4 + j
    const int fq = lane >> 4;
    #pragma unroll
    for (int n = 0; n < NB; ++n) {
        const long col = colB + wc + n*16 + fr;
        const float bn = HAS_BIAS ? bias[col] : 0.0f;
        #pragma unroll
        for (int m = 0; m < 4; ++m) {
            const long row0 = rowA + wr + m*16 + fq*4;
            #pragma unroll
            for (int j = 0; j < 4; ++j) {
                float x = acc[m][n][j] + bn;
                if (ACT == 1) x = fmaxf(x, 0.0f);
                Cz[(row0 + j) * (long)ldc + col] = x;
            }
        }
    }
}

// ---------------- GAT1 attention (round-14 verbatim) -------------------------
__global__ __launch_bounds__(256)
void gat1_attn_kernel(float* __restrict__ h1,
                      const int* __restrict__ missing,
                      const float* __restrict__ attl, const float* __restrict__ attr,
                      const float* __restrict__ bias)
{
    const int gtid = blockIdx.x * 256 + threadIdx.x;
    const int wid  = gtid >> 6;
    const int lane = threadIdx.x & 63;
    const int b = wid >> 2;
    const int h = wid & 3;
    const int cb = h * 128 + lane;
    float* base = h1 + (size_t)b * 2048 + cb;

    float hr[4][2];
    #pragma unroll
    for (int j = 0; j < 4; ++j) { hr[j][0] = base[j*512]; hr[j][1] = base[j*512 + 64]; }
    const float al0 = attl[cb], al1 = attl[cb+64];
    const float ar0 = attr[cb], ar1 = attr[cb+64];

    float red[18];
    #pragma unroll
    for (int i = 0; i < 4; ++i)
        #pragma unroll
        for (int j = i; j < 4; ++j)
            red[SYM(i,j)] = hr[i][0]*hr[j][0] + hr[i][1]*hr[j][1];
    #pragma unroll
    for (int j = 0; j < 4; ++j) {
        red[10+j] = hr[j][0]*al0 + hr[j][1]*al1;
        red[14+j] = hr[j][0]*ar0 + hr[j][1]*ar1;
    }
    #pragma unroll
    for (int m = 1; m < 64; m <<= 1)
        #pragma unroll
        for (int r = 0; r < 18; ++r)
            red[r] += __shfl_xor(red[r], m, 64);

    const int miss = missing[b];
    bool pres[4];
    #pragma unroll
    for (int mm = 0; mm < 4; ++mm) pres[mm] = (miss != mm + 1);

    float attn[4][4];
    #pragma unroll
    for (int i = 0; i < 4; ++i) {
        float av[4]; float mx = -3.4e38f;
        #pragma unroll
        for (int j = 0; j < 4; ++j) {
            const bool mk = (i == j) || (pres[i] && pres[j]);
            const float l = (i <= j) ? red[SYM(i,j)] : red[SYM(j,i)];
            float v = (red[14+i] + red[10+j]) * sigmoidf_(l);
            v = (v >= 0.0f) ? v : 0.2f * v;
            av[j] = mk ? v : -1e30f;
            mx = fmaxf(mx, av[j]);
        }
        float den = 0.0f;
        #pragma unroll
        for (int j = 0; j < 4; ++j) { av[j] = __expf(av[j] - mx); den += av[j]; }
        const float inv = 1.0f / den;
        #pragma unroll
        for (int j = 0; j < 4; ++j) attn[i][j] = av[j] * inv;
    }

    const float b0 = bias[cb], b1 = bias[cb+64];
    #pragma unroll
    for (int i = 0; i < 4; ++i) {
        float o0 = b0, o1 = b1;
        #pragma unroll
        for (int j = 0; j < 4; ++j) { o0 += attn[i][j]*hr[j][0]; o1 += attn[i][j]*hr[j][1]; }
        base[i*512]      = gelu_(o0);
        base[i*512 + 64] = gelu_(o1);
    }
}

// ------- GAT2 attention + pool + LayerNorm (round-14 verbatim) ---------------
__global__ __launch_bounds__(256)
void gat2_attn_kernel(const float* __restrict__ h2,
                      const int* __restrict__ missing,
                      const float* __restrict__ attl, const float* __restrict__ attr,
                      const float* __restrict__ bias,
                      const float* __restrict__ lng, const float* __restrict__ lnb,
                      float* __restrict__ normed)
{
    const int gtid = blockIdx.x * 256 + threadIdx.x;
    const int b = gtid >> 6;
    const int lane = threadIdx.x & 63;
    const float4* hp = (const float4*)(h2 + (size_t)b * 1024);

    float4 hr[4];
    #pragma unroll
    for (int j = 0; j < 4; ++j) hr[j] = hp[j*64 + lane];
    const float4 al = ((const float4*)attl)[lane];
    const float4 ar = ((const float4*)attr)[lane];

    float red[18];
    #pragma unroll
    for (int i = 0; i < 4; ++i)
        #pragma unroll
        for (int j = i; j < 4; ++j)
            red[SYM(i,j)] = hr[i].x*hr[j].x + hr[i].y*hr[j].y + hr[i].z*hr[j].z + hr[i].w*hr[j].w;
    #pragma unroll
    for (int j = 0; j < 4; ++j) {
        red[10+j] = hr[j].x*al.x + hr[j].y*al.y + hr[j].z*al.z + hr[j].w*al.w;
        red[14+j] = hr[j].x*ar.x + hr[j].y*ar.y + hr[j].z*ar.z + hr[j].w*ar.w;
    }
    #pragma unroll
    for (int m = 1; m < 64; m <<= 1)
        #pragma unroll
        for (int r = 0; r < 18; ++r)
            red[r] += __shfl_xor(red[r], m, 64);

    const int miss = missing[b];
    bool pres[4];
    #pragma unroll
    for (int mm = 0; mm < 4; ++mm) pres[mm] = (miss != mm + 1);

    float wsum[4] = {0.f, 0.f, 0.f, 0.f};
    #pragma unroll
    for (int i = 0; i < 4; ++i) {
        float av[4]; float mx = -3.4e38f;
        #pragma unroll
        for (int j = 0; j < 4; ++j) {
            const bool mk = (i == j) || (pres[i] && pres[j]);
            const float l = (i <= j) ? red[SYM(i,j)] : red[SYM(j,i)];
            float v = (red[14+i] + red[10+j]) * sigmoidf_(l);
            v = (v >= 0.0f) ? v : 0.2f * v;
            av[j] = mk ? v : -1e30f;
            mx = fmaxf(mx, av[j]);
        }
        float den = 0.0f;
        #pragma unroll
        for (int j = 0; j < 4; ++j) { av[j] = __expf(av[j] - mx); den += av[j]; }
        const float inv = 0.25f / den;
        #pragma unroll
        for (int j = 0; j < 4; ++j) wsum[j] += av[j] * inv;
    }

    const float4 bv = ((const float4*)bias)[lane];
    float pooled[4] = {bv.x, bv.y, bv.z, bv.w};
    #pragma unroll
    for (int j = 0; j < 4; ++j) {
        pooled[0] += wsum[j] * hr[j].x;
        pooled[1] += wsum[j] * hr[j].y;
        pooled[2] += wsum[j] * hr[j].z;
        pooled[3] += wsum[j] * hr[j].w;
    }

    float s1 = pooled[0] + pooled[1] + pooled[2] + pooled[3];
    float s2 = pooled[0]*pooled[0] + pooled[1]*pooled[1] + pooled[2]*pooled[2] + pooled[3]*pooled[3];
    #pragma unroll
    for (int m = 1; m < 64; m <<= 1) {
        s1 += __shfl_xor(s1, m, 64);
        s2 += __shfl_xor(s2, m, 64);
    }
    const float mu   = s1 * (1.0f / 256.0f);
    const float var  = s2 * (1.0f / 256.0f) - mu * mu;
    const float rstd = rsqrtf(var + 1e-5f);
    const float4 g  = ((const float4*)lng)[lane];
    const float4 bb = ((const float4*)lnb)[lane];
    float4 o;
    o.x = (pooled[0] - mu) * rstd * g.x + bb.x;
    o.y = (pooled[1] - mu) * rstd * g.y + bb.y;
    o.z = (pooled[2] - mu) * rstd * g.z + bb.z;
    o.w = (pooled[3] - mu) * rstd * g.w + bb.w;
    ((float4*)normed)[(size_t)b * 64 + lane] = o;
}

// ---------------- head2 (round-4 verbatim) ----------------------------------
__global__ __launch_bounds__(256)
void head2_kernel(const float* __restrict__ hid, const float* __restrict__ W2,
                  const float* __restrict__ b2, float* __restrict__ out)
{
    const int t = blockIdx.x * 256 + threadIdx.x;
    const int b = t >> 3, o = t & 7;
    const float4* hp = (const float4*)(hid + (size_t)b * 256);
    const float4* wp = (const float4*)(W2 + o * 256);
    float acc = b2[o];
    #pragma unroll 8
    for (int c = 0; c < 64; ++c) {
        const float4 hv = hp[c], wv = wp[c];
        acc += hv.x*wv.x + hv.y*wv.y + hv.z*wv.z + hv.w*wv.w;
    }
    out[t] = acc;
}

// ---------------- launch ----------------------------------------------------
extern "C" void kernel_launch(void* const* d_in, const int* in_sizes, int n_in,
                              void* d_out, int out_size, void* d_ws, size_t ws_size,
                              hipStream_t stream)
{
    (void)in_sizes; (void)n_in; (void)out_size; (void)ws_size;
    const int*   miss  = (const int*)d_in[4];
    const float* g1_al = (const float*)d_in[14];
    const float* g1_ar = (const float*)d_in[15];
    const float* g1_b  = (const float*)d_in[16];
    const float* g2_al = (const float*)d_in[18];
    const float* g2_ar = (const float*)d_in[19];
    const float* g2_b  = (const float*)d_in[20];
    const float* ln_g  = (const float*)d_in[21];
    const float* ln_b  = (const float*)d_in[22];
    const float* h_W2  = (const float*)d_in[25];
    const float* h_b2  = (const float*)d_in[26];
    float* out = (float*)d_out;

    // workspace (MiB offsets; peak 180 MiB < proven 192 MiB):
    //   wf16   @   0 (2.75)
    //   feats  @   4 fp32 [16384,1024] (64)
    //   h1c    @  68 fp32 [32768,512]  (64)   (hid overlaps after h1c dies)
    //   h2c    @ 132 fp32 [32768,256]  (32)
    //   normed @ 164 fp32 [16384,256]  (16)
    char* base = (char*)d_ws;
    half_t* wf16   = (half_t*)(base);
    float*  feats  = (float*)(base + (4ll   << 20));
    float*  h1c    = (float*)(base + (68ll  << 20));
    float*  h2c    = (float*)(base + (132ll << 20));
    float*  normed = (float*)(base + (164ll << 20));
    float*  hid    = (float*)(base + (68ll  << 20));   // overlaps dead h1c

    const dim3 blk(256);

    P8 wsrc = {{d_in[5], d_in[7], d_in[9], d_in[11], d_in[13], d_in[17], d_in[23], d_in[23]}};
    cvt_weights<<<dim3(64, 7), blk, 0, stream>>>(wsrc, wf16);

    // 1) projections (z-batched), BN=256: feats[B,4,256] fp32
    P4 Xs  = {{d_in[0], d_in[1], d_in[2], d_in[3]}};
    P4 bms = {{d_in[6], d_in[8], d_in[10], d_in[12]}};
    gemm_bf<256, 0, true><<<dim3(1, 128, 4), blk, 0, stream>>>(
        Xs, wf16, 262144, bms, feats, /*K=*/1024, /*lda=*/1024, /*ldc=*/1024, /*zofs=*/256);

    P4 NUL = {{nullptr, nullptr, nullptr, nullptr}};

    // 2) mid-section, 2 chunks of 8192 samples (32768 node-rows) [r6-validated]
    for (int c = 0; c < 2; ++c) {
        const long roff = (long)c * 32768;
        const int  soff = c * 8192;

        // gat1 linear: h1c[32768,512] = feats_chunk @ g1_W^T (fp16 W)
        P4 Ac = {{feats + roff * 256, nullptr, nullptr, nullptr}};
        gemm_bf<256, 0, false><<<dim3(2, 256, 1), blk, 0, stream>>>(
            Ac, wf16 + 1048576, 0, NUL, h1c, 256, 256, 512, 0);

        // gat1 attention + bias + gelu (in-place fp32)
        gat1_attn_kernel<<<dim3(8192), blk, 0, stream>>>(
            h1c, miss + soff, g1_al, g1_ar, g1_b);

        // gat2 linear: h2c[32768,256] = h1c @ g2_W^T (fp16 W)
        P4 Hc = {{h1c, nullptr, nullptr, nullptr}};
        gemm_bf<256, 0, false><<<dim3(1, 256, 1), blk, 0, stream>>>(
            Hc, wf16 + 1179648, 0, NUL, h2c, 512, 512, 256, 0);

        // gat2 attention + pool + layernorm -> normed chunk fp32
        gat2_attn_kernel<<<dim3(2048), blk, 0, stream>>>(
            h2c, miss + soff, g2_al, g2_ar, g2_b, ln_g, ln_b,
            normed + (size_t)soff * 256);
    }

    // 3) head1: hid = relu(normed @ h_W1^T + h_b1) (fp16 W)
    P4 N4  = {{normed, nullptr, nullptr, nullptr}};
    P4 HB1 = {{d_in[24], nullptr, nullptr, nullptr}};
    gemm_bf<256, 1, true><<<dim3(1, 128, 1), blk, 0, stream>>>(
        N4, wf16 + 1310720, 0, HB1, hid, 256, 256, 256, 0);

    // 4) head2: out[16384,8]
    head2_kernel<<<dim3(512), blk, 0, stream>>>(hid, h_W2, h_b2, out);
}

// Round 16
// 414.416 us; speedup vs baseline: 1.1003x; 1.1003x over previous
//
#include <hip/hip_runtime.h>

// B=16384, FEAT=1024, FD=256, M=4 nodes, H1=4x128 (concat->512), H2=1x256, OUT=8.
// Round 16: r14 base (best, 376us); ONE change: GEMM staging via
// __builtin_amdgcn_global_load_lds (DMA global->LDS, raw fp32 A and B),
// single-buffered 2-barrier loop (m97 structure), fp32->fp16 cvt moved to
// fragment build (same values, same RNE cast -> bit-identical math).
// XOR swizzle: linear LDS dest + inverse-swizzled SOURCE + swizzled READ.

typedef __attribute__((ext_vector_type(8))) _Float16 f16x8;
typedef __attribute__((ext_vector_type(4))) float f32x4;

struct P4 { const float* p[4]; };

#define SYM(i,j) ((i)*(7-(i))/2 + (j))

__device__ __forceinline__ float sigmoidf_(float x) { return 1.0f / (1.0f + __expf(-x)); }
__device__ __forceinline__ float gelu_(float x) {
    return 0.5f * x * (1.0f + erff(x * 0.70710678118654752440f));
}

__device__ __forceinline__ void gload16(const void* g, void* l) {
    __builtin_amdgcn_global_load_lds(
        (const __attribute__((address_space(1))) void*)g,
        (__attribute__((address_space(3))) void*)l, 16, 0, 0);
}

// ---- fp16-MFMA NT GEMM: C[M,N] f32 = act(A[M,K] f32 @ W[N,K]^T f32 + bias) --
// BM=BN=128, BK=32, 256 threads = 4 waves (2x2), wave tile 64x64.
// Staging: global_load_lds dwordx4, fp32 tiles [128][32] (16KB each).
//  - wave w, issue q: LDS base = row (w*32+q*8), lane l -> row +=l>>3, slot l&7
//  - source slot sg = (l&7) ^ (l>>3)   [= slot ^ (row&7), since row&7 == l>>3]
//  - read: global slot s of row r lives at LDS slot s ^ (r&7)
template<int ACT, bool HAS_BIAS>
__global__ __launch_bounds__(256)
void gemm_nt_mfma(P4 A4, P4 W4, P4 b4, float* __restrict__ C,
                  int K, int lda, int ldc, int zofs)
{
    __shared__ __align__(16) float AsF[128][32];
    __shared__ __align__(16) float BsF[128][32];
    const int z = blockIdx.z;
    const float* __restrict__ A    = A4.p[z];
    const float* __restrict__ Bw   = W4.p[z];
    const float* __restrict__ bias = b4.p[z];
    float* __restrict__ Cz = C + (long)z * zofs;

    const int t    = threadIdx.x;
    const int lane = t & 63;
    const int w    = t >> 6;
    const int wr   = (w >> 1) << 6;
    const int wc   = (w & 1) << 6;
    const long rowA = (long)blockIdx.y * 128;
    const long colB = (long)blockIdx.x * 128;

    // staging source pointers (swizzled slot), one per issue q=0..3
    const int lrow = lane >> 3;               // 0..7 within chunk
    const int sg   = (lane & 7) ^ lrow;       // swizzled source slot
    const float* Asrc[4];
    const float* Bsrc[4];
    float* Adst[4];
    float* Bdst[4];
    #pragma unroll
    for (int q = 0; q < 4; ++q) {
        const int r = w * 32 + q * 8 + lrow;  // tile row this lane feeds
        Asrc[q] = A  + (rowA + r) * (long)lda + sg * 4;
        Bsrc[q] = Bw + (colB + r) * (long)K   + sg * 4;
        Adst[q] = &AsF[w * 32 + q * 8][0];    // wave-uniform LDS base
        Bdst[q] = &BsF[w * 32 + q * 8][0];
    }

    const int fr = lane & 15;
    const int fq = lane >> 4;
    const int s0 = fq << 1;                   // first dwordx4 slot of fragment

    f32x4 acc[4][4] = {};

    for (int k0 = 0; k0 < K; k0 += 32) {
        // ---- DMA stage tile k0 (8 x wave-level 1KB) ----
        #pragma unroll
        for (int q = 0; q < 4; ++q) gload16(Asrc[q] + k0, Adst[q]);
        #pragma unroll
        for (int q = 0; q < 4; ++q) gload16(Bsrc[q] + k0, Bdst[q]);
        __syncthreads();                      // vmcnt drain + barrier

        // ---- fragments (swizzled read + cvt) + MFMA ----
        f16x8 af[4], bf[4];
        #pragma unroll
        for (int m = 0; m < 4; ++m) {
            const int r = wr + m*16 + fr, r7 = r & 7;
            const float4 x0 = *(const float4*)&AsF[r][( s0      ^ r7) << 2];
            const float4 x1 = *(const float4*)&AsF[r][((s0 + 1) ^ r7) << 2];
            af[m][0] = (_Float16)x0.x; af[m][1] = (_Float16)x0.y;
            af[m][2] = (_Float16)x0.z; af[m][3] = (_Float16)x0.w;
            af[m][4] = (_Float16)x1.x; af[m][5] = (_Float16)x1.y;
            af[m][6] = (_Float16)x1.z; af[m][7] = (_Float16)x1.w;
        }
        #pragma unroll
        for (int n = 0; n < 4; ++n) {
            const int r = wc + n*16 + fr, r7 = r & 7;
            const float4 x0 = *(const float4*)&BsF[r][( s0      ^ r7) << 2];
            const float4 x1 = *(const float4*)&BsF[r][((s0 + 1) ^ r7) << 2];
            bf[n][0] = (_Float16)x0.x; bf[n][1] = (_Float16)x0.y;
            bf[n][2] = (_Float16)x0.z; bf[n][3] = (_Float16)x0.w;
            bf[n][4] = (_Float16)x1.x; bf[n][5] = (_Float16)x1.y;
            bf[n][6] = (_Float16)x1.z; bf[n][7] = (_Float16)x1.w;
        }
        #pragma unroll
        for (int m = 0; m < 4; ++m)
            #pragma unroll
            for (int n = 0; n < 4; ++n)
                acc[m][n] = __builtin_amdgcn_mfma_f32_16x16x32_f16(af[m], bf[n], acc[m][n], 0, 0, 0);
        __syncthreads();                      // protect LDS overwrite
    }

    // ---- epilogue: col = lane&15, row = (lane>>4)*4 + j ----
    #pragma unroll
    for (int n = 0; n < 4; ++n) {
        const long col = colB + wc + n*16 + fr;
        const float bn = HAS_BIAS ? bias[col] : 0.0f;
        #pragma unroll
        for (int m = 0; m < 4; ++m) {
            const long row0 = rowA + wr + m*16 + fq*4;
            #pragma unroll
            for (int j = 0; j < 4; ++j) {
                float x = acc[m][n][j] + bn;
                if (ACT == 1) x = fmaxf(x, 0.0f);
                Cz[(row0 + j) * (long)ldc + col] = x;
            }
        }
    }
}

// ---------------- GAT1 attention (round-14 verbatim) -------------------------
__global__ __launch_bounds__(256)
void gat1_attn_kernel(float* __restrict__ h1,
                      const int* __restrict__ missing,
                      const float* __restrict__ attl, const float* __restrict__ attr,
                      const float* __restrict__ bias)
{
    const int gtid = blockIdx.x * 256 + threadIdx.x;
    const int wid  = gtid >> 6;
    const int lane = threadIdx.x & 63;
    const int b = wid >> 2;
    const int h = wid & 3;
    const int cb = h * 128 + lane;
    float* base = h1 + (size_t)b * 2048 + cb;

    float hr[4][2];
    #pragma unroll
    for (int j = 0; j < 4; ++j) { hr[j][0] = base[j*512]; hr[j][1] = base[j*512 + 64]; }
    const float al0 = attl[cb], al1 = attl[cb+64];
    const float ar0 = attr[cb], ar1 = attr[cb+64];

    float red[18];
    #pragma unroll
    for (int i = 0; i < 4; ++i)
        #pragma unroll
        for (int j = i; j < 4; ++j)
            red[SYM(i,j)] = hr[i][0]*hr[j][0] + hr[i][1]*hr[j][1];
    #pragma unroll
    for (int j = 0; j < 4; ++j) {
        red[10+j] = hr[j][0]*al0 + hr[j][1]*al1;
        red[14+j] = hr[j][0]*ar0 + hr[j][1]*ar1;
    }
    #pragma unroll
    for (int m = 1; m < 64; m <<= 1)
        #pragma unroll
        for (int r = 0; r < 18; ++r)
            red[r] += __shfl_xor(red[r], m, 64);

    const int miss = missing[b];
    bool pres[4];
    #pragma unroll
    for (int mm = 0; mm < 4; ++mm) pres[mm] = (miss != mm + 1);

    float attn[4][4];
    #pragma unroll
    for (int i = 0; i < 4; ++i) {
        float av[4]; float mx = -3.4e38f;
        #pragma unroll
        for (int j = 0; j < 4; ++j) {
            const bool mk = (i == j) || (pres[i] && pres[j]);
            const float l = (i <= j) ? red[SYM(i,j)] : red[SYM(j,i)];
            float v = (red[14+i] + red[10+j]) * sigmoidf_(l);
            v = (v >= 0.0f) ? v : 0.2f * v;
            av[j] = mk ? v : -1e30f;
            mx = fmaxf(mx, av[j]);
        }
        float den = 0.0f;
        #pragma unroll
        for (int j = 0; j < 4; ++j) { av[j] = __expf(av[j] - mx); den += av[j]; }
        const float inv = 1.0f / den;
        #pragma unroll
        for (int j = 0; j < 4; ++j) attn[i][j] = av[j] * inv;
    }

    const float b0 = bias[cb], b1 = bias[cb+64];
    #pragma unroll
    for (int i = 0; i < 4; ++i) {
        float o0 = b0, o1 = b1;
        #pragma unroll
        for (int j = 0; j < 4; ++j) { o0 += attn[i][j]*hr[j][0]; o1 += attn[i][j]*hr[j][1]; }
        base[i*512]      = gelu_(o0);
        base[i*512 + 64] = gelu_(o1);
    }
}

// ------- GAT2 attention + pool + LayerNorm (round-14 verbatim) ---------------
__global__ __launch_bounds__(256)
void gat2_attn_kernel(const float* __restrict__ h2,
                      const int* __restrict__ missing,
                      const float* __restrict__ attl, const float* __restrict__ attr,
                      const float* __restrict__ bias,
                      const float* __restrict__ lng, const float* __restrict__ lnb,
                      float* __restrict__ normed)
{
    const int gtid = blockIdx.x * 256 + threadIdx.x;
    const int b = gtid >> 6;
    const int lane = threadIdx.x & 63;
    const float4* hp = (const float4*)(h2 + (size_t)b * 1024);

    float4 hr[4];
    #pragma unroll
    for (int j = 0; j < 4; ++j) hr[j] = hp[j*64 + lane];
    const float4 al = ((const float4*)attl)[lane];
    const float4 ar = ((const float4*)attr)[lane];

    float red[18];
    #pragma unroll
    for (int i = 0; i < 4; ++i)
        #pragma unroll
        for (int j = i; j < 4; ++j)
            red[SYM(i,j)] = hr[i].x*hr[j].x + hr[i].y*hr[j].y + hr[i].z*hr[j].z + hr[i].w*hr[j].w;
    #pragma unroll
    for (int j = 0; j < 4; ++j) {
        red[10+j] = hr[j].x*al.x + hr[j].y*al.y + hr[j].z*al.z + hr[j].w*al.w;
        red[14+j] = hr[j].x*ar.x + hr[j].y*ar.y + hr[j].z*ar.z + hr[j].w*ar.w;
    }
    #pragma unroll
    for (int m = 1; m < 64; m <<= 1)
        #pragma unroll
        for (int r = 0; r < 18; ++r)
            red[r] += __shfl_xor(red[r], m, 64);

    const int miss = missing[b];
    bool pres[4];
    #pragma unroll
    for (int mm = 0; mm < 4; ++mm) pres[mm] = (miss != mm + 1);

    float wsum[4] = {0.f, 0.f, 0.f, 0.f};
    #pragma unroll
    for (int i = 0; i < 4; ++i) {
        float av[4]; float mx = -3.4e38f;
        #pragma unroll
        for (int j = 0; j < 4; ++j) {
            const bool mk = (i == j) || (pres[i] && pres[j]);
            const float l = (i <= j) ? red[SYM(i,j)] : red[SYM(j,i)];
            float v = (red[14+i] + red[10+j]) * sigmoidf_(l);
            v = (v >= 0.0f) ? v : 0.2f * v;
            av[j] = mk ? v : -1e30f;
            mx = fmaxf(mx, av[j]);
        }
        float den = 0.0f;
        #pragma unroll
        for (int j = 0; j < 4; ++j) { av[j] = __expf(av[j] - mx); den += av[j]; }
        const float inv = 0.25f / den;
        #pragma unroll
        for (int j = 0; j < 4; ++j) wsum[j] += av[j] * inv;
    }

    const float4 bv = ((const float4*)bias)[lane];
    float pooled[4] = {bv.x, bv.y, bv.z, bv.w};
    #pragma unroll
    for (int j = 0; j < 4; ++j) {
        pooled[0] += wsum[j] * hr[j].x;
        pooled[1] += wsum[j] * hr[j].y;
        pooled[2] += wsum[j] * hr[j].z;
        pooled[3] += wsum[j] * hr[j].w;
    }

    float s1 = pooled[0] + pooled[1] + pooled[2] + pooled[3];
    float s2 = pooled[0]*pooled[0] + pooled[1]*pooled[1] + pooled[2]*pooled[2] + pooled[3]*pooled[3];
    #pragma unroll
    for (int m = 1; m < 64; m <<= 1) {
        s1 += __shfl_xor(s1, m, 64);
        s2 += __shfl_xor(s2, m, 64);
    }
    const float mu   = s1 * (1.0f / 256.0f);
    const float var  = s2 * (1.0f / 256.0f) - mu * mu;
    const float rstd = rsqrtf(var + 1e-5f);
    const float4 g  = ((const float4*)lng)[lane];
    const float4 bb = ((const float4*)lnb)[lane];
    float4 o;
    o.x = (pooled[0] - mu) * rstd * g.x + bb.x;
    o.y = (pooled[1] - mu) * rstd * g.y + bb.y;
    o.z = (pooled[2] - mu) * rstd * g.z + bb.z;
    o.w = (pooled[3] - mu) * rstd * g.w + bb.w;
    ((float4*)normed)[(size_t)b * 64 + lane] = o;
}

// ---------------- head2 (round-4 verbatim) ----------------------------------
__global__ __launch_bounds__(256)
void head2_kernel(const float* __restrict__ hid, const float* __restrict__ W2,
                  const float* __restrict__ b2, float* __restrict__ out)
{
    const int t = blockIdx.x * 256 + threadIdx.x;
    const int b = t >> 3, o = t & 7;
    const float4* hp = (const float4*)(hid + (size_t)b * 256);
    const float4* wp = (const float4*)(W2 + o * 256);
    float acc = b2[o];
    #pragma unroll 8
    for (int c = 0; c < 64; ++c) {
        const float4 hv = hp[c], wv = wp[c];
        acc += hv.x*wv.x + hv.y*wv.y + hv.z*wv.z + hv.w*wv.w;
    }
    out[t] = acc;
}

// ---------------- launch (round-4/14 verbatim) -------------------------------
extern "C" void kernel_launch(void* const* d_in, const int* in_sizes, int n_in,
                              void* d_out, int out_size, void* d_ws, size_t ws_size,
                              hipStream_t stream)
{
    (void)in_sizes; (void)n_in; (void)out_size; (void)ws_size;
    const float* X0 = (const float*)d_in[0];
    const float* X1 = (const float*)d_in[1];
    const float* X2 = (const float*)d_in[2];
    const float* X3 = (const float*)d_in[3];
    const int*   miss  = (const int*)d_in[4];
    const float* g1_W  = (const float*)d_in[13];
    const float* g1_al = (const float*)d_in[14];
    const float* g1_ar = (const float*)d_in[15];
    const float* g1_b  = (const float*)d_in[16];
    const float* g2_W  = (const float*)d_in[17];
    const float* g2_al = (const float*)d_in[18];
    const float* g2_ar = (const float*)d_in[19];
    const float* g2_b  = (const float*)d_in[20];
    const float* ln_g  = (const float*)d_in[21];
    const float* ln_b  = (const float*)d_in[22];
    const float* h_W1  = (const float*)d_in[23];
    const float* h_b1  = (const float*)d_in[24];
    const float* h_W2  = (const float*)d_in[25];
    const float* h_b2  = (const float*)d_in[26];
    float* out = (float*)d_out;

    float* ws     = (float*)d_ws;
    float* feats  = ws;
    float* h1     = ws + 16777216;
    float* h2     = ws;
    float* normed = ws + 16777216;
    float* hid    = normed + 4194304;

    const dim3 blk(256);

    P4 Xs  = {{X0, X1, X2, X3}};
    P4 Wms = {{(const float*)d_in[5], (const float*)d_in[7],
               (const float*)d_in[9], (const float*)d_in[11]}};
    P4 bms = {{(const float*)d_in[6], (const float*)d_in[8],
               (const float*)d_in[10], (const float*)d_in[12]}};
    P4 F4  = {{feats, feats, feats, feats}};
    P4 G1W = {{g1_W, g1_W, g1_W, g1_W}};
    P4 H14 = {{h1, h1, h1, h1}};
    P4 G2W = {{g2_W, g2_W, g2_W, g2_W}};
    P4 N4  = {{normed, normed, normed, normed}};
    P4 HW1 = {{h_W1, h_W1, h_W1, h_W1}};
    P4 HB1 = {{h_b1, h_b1, h_b1, h_b1}};
    P4 NUL = {{nullptr, nullptr, nullptr, nullptr}};

    // 1) per-modality projections (z-batched): feats[B,4,256]
    gemm_nt_mfma<0, true><<<dim3(2, 128, 4), blk, 0, stream>>>(
        Xs, Wms, bms, feats, /*K=*/1024, /*lda=*/1024, /*ldc=*/1024, /*zofs=*/256);

    // 2) gat1 linear: h1[65536,512] = feats[65536,256] @ g1_W^T
    gemm_nt_mfma<0, false><<<dim3(4, 512, 1), blk, 0, stream>>>(
        F4, G1W, NUL, h1, 256, 256, 512, 0);

    // 3) gat1 attention + bias + gelu (in-place on h1)
    gat1_attn_kernel<<<dim3(16384), blk, 0, stream>>>(h1, miss, g1_al, g1_ar, g1_b);

    // 4) gat2 linear: h2[65536,256] = x1[65536,512] @ g2_W^T
    gemm_nt_mfma<0, false><<<dim3(2, 512, 1), blk, 0, stream>>>(
        H14, G2W, NUL, h2, 512, 512, 256, 0);

    // 5) gat2 attention + pool + layernorm -> normed[16384,256]
    gat2_attn_kernel<<<dim3(4096), blk, 0, stream>>>(
        h2, miss, g2_al, g2_ar, g2_b, ln_g, ln_b, normed);

    // 6) head1: hid = relu(normed @ h_W1^T + h_b1)
    gemm_nt_mfma<1, true><<<dim3(2, 128, 1), blk, 0, stream>>>(
        N4, HW1, HB1, hid, 256, 256, 256, 0);

    // 7) head2: out[16384,8]
    head2_kernel<<<dim3(512), blk, 0, stream>>>(hid, h_W2, h_b2, out);
}

// Round 17
// 377.720 us; speedup vs baseline: 1.2072x; 1.0972x over previous
//
#include <hip/hip_runtime.h>

// B=16384, FEAT=1024, FD=256, M=4 nodes, H1=4x128 (concat->512), H2=1x256, OUT=8.
// Round 17: r14 base (best, 376us) + ONE change: in the GEMM K-loop, replace
// __syncthreads() (which makes hipcc emit s_waitcnt vmcnt(0) lgkmcnt(0) and
// drains the prefetch) with explicit lgkmcnt(0) + raw s_barrier +
// sched_barrier(0). Global prefetch loads stay in flight across the barrier.
// FP values/order unchanged -> bit-identical to r14.

typedef __attribute__((ext_vector_type(8))) _Float16 f16x8;
typedef __attribute__((ext_vector_type(4))) float f32x4;

struct P4 { const float* p[4]; };

#define SYM(i,j) ((i)*(7-(i))/2 + (j))

__device__ __forceinline__ float sigmoidf_(float x) { return 1.0f / (1.0f + __expf(-x)); }
__device__ __forceinline__ float gelu_(float x) {
    return 0.5f * x * (1.0f + erff(x * 0.70710678118654752440f));
}

// barrier that does NOT drain vmcnt: LDS ops fenced, global loads stay in flight
__device__ __forceinline__ void barrier_lds_only() {
    asm volatile("s_waitcnt lgkmcnt(0)" ::: "memory");
    __builtin_amdgcn_s_barrier();
    __builtin_amdgcn_sched_barrier(0);
}

// ---------------- fp16-MFMA NT GEMM (r13 2-ahead schedule, lds-only barrier) -
// Schedule per iter k: [ds_write tile k+1 (regs from iter k-1)] ->
//                      [issue loads tile k+2] -> [MFMA buf k] -> [barrier*]
template<int ACT, bool HAS_BIAS>
__global__ __launch_bounds__(256)
void gemm_nt_mfma(P4 A4, P4 W4, P4 b4, float* __restrict__ C,
                  int K, int lda, int ldc, int zofs)
{
    __shared__ __align__(16) _Float16 As[2][128][32];
    __shared__ __align__(16) _Float16 Bs[2][128][32];
    const int z = blockIdx.z;
    const float* __restrict__ A    = A4.p[z];
    const float* __restrict__ Bw   = W4.p[z];
    const float* __restrict__ bias = b4.p[z];
    float* __restrict__ Cz = C + (long)z * zofs;

    const int t    = threadIdx.x;
    const int lane = t & 63;
    const int w    = t >> 6;
    const int wr   = (w >> 1) << 6;
    const int wc   = (w & 1) << 6;
    const long rowA = (long)blockIdx.y * 128;
    const long colB = (long)blockIdx.x * 128;

    const float* Apt[4];
    const float* Bpt[4];
    int rr[4], cc[4];
    #pragma unroll
    for (int i = 0; i < 4; ++i) {
        const int f = t + i * 256;
        rr[i] = f >> 3;
        cc[i] = (f & 7) << 2;
        Apt[i] = A  + (rowA + rr[i]) * (long)lda + cc[i];
        Bpt[i] = Bw + (colB + rr[i]) * (long)K   + cc[i];
    }

    f32x4 acc[4][4] = {};
    const int NK = K >> 5;

    float4 aP[4], bP[4], aN[4], bN[4];
    #pragma unroll
    for (int i = 0; i < 4; ++i) {
        aP[i] = *(const float4*)(Apt[i]);
        bP[i] = *(const float4*)(Bpt[i]);
    }
    #pragma unroll
    for (int i = 0; i < 4; ++i) {
        union { _Float16 h[4]; uint2 u; } pa, pb;
        pa.h[0] = (_Float16)aP[i].x; pa.h[1] = (_Float16)aP[i].y;
        pa.h[2] = (_Float16)aP[i].z; pa.h[3] = (_Float16)aP[i].w;
        pb.h[0] = (_Float16)bP[i].x; pb.h[1] = (_Float16)bP[i].y;
        pb.h[2] = (_Float16)bP[i].z; pb.h[3] = (_Float16)bP[i].w;
        *(uint2*)&As[0][rr[i]][cc[i]] = pa.u;
        *(uint2*)&Bs[0][rr[i]][cc[i]] = pb.u;
    }
    if (NK > 1) {
        #pragma unroll
        for (int i = 0; i < 4; ++i) {
            aP[i] = *(const float4*)(Apt[i] + 32);
            bP[i] = *(const float4*)(Bpt[i] + 32);
        }
    }
    barrier_lds_only();

    const int fr = lane & 15;
    const int fg = (lane >> 4) << 3;

    for (int kk = 0; kk < NK; ++kk) {
        const int cur = kk & 1, nxt = cur ^ 1;

        // 1) write tile kk+1 (regs loaded a full iteration ago) -> buf[nxt]
        if (kk + 1 < NK) {
            #pragma unroll
            for (int i = 0; i < 4; ++i) {
                union { _Float16 h[4]; uint2 u; } pa, pb;
                pa.h[0] = (_Float16)aP[i].x; pa.h[1] = (_Float16)aP[i].y;
                pa.h[2] = (_Float16)aP[i].z; pa.h[3] = (_Float16)aP[i].w;
                pb.h[0] = (_Float16)bP[i].x; pb.h[1] = (_Float16)bP[i].y;
                pb.h[2] = (_Float16)bP[i].z; pb.h[3] = (_Float16)bP[i].w;
                *(uint2*)&As[nxt][rr[i]][cc[i]] = pa.u;
                *(uint2*)&Bs[nxt][rr[i]][cc[i]] = pb.u;
            }
        }

        // 2) issue loads for tile kk+2 (stay in flight across the barrier)
        if (kk + 2 < NK) {
            const int ko = (kk + 2) << 5;
            #pragma unroll
            for (int i = 0; i < 4; ++i) {
                aN[i] = *(const float4*)(Apt[i] + ko);
                bN[i] = *(const float4*)(Bpt[i] + ko);
            }
        }

        // 3) fragments + MFMA on buf[cur]
        f16x8 af[4], bf[4];
        #pragma unroll
        for (int m = 0; m < 4; ++m) af[m] = *(const f16x8*)&As[cur][wr + m*16 + fr][fg];
        #pragma unroll
        for (int n = 0; n < 4; ++n) bf[n] = *(const f16x8*)&Bs[cur][wc + n*16 + fr][fg];
        #pragma unroll
        for (int m = 0; m < 4; ++m)
            #pragma unroll
            for (int n = 0; n < 4; ++n)
                acc[m][n] = __builtin_amdgcn_mfma_f32_16x16x32_f16(af[m], bf[n], acc[m][n], 0, 0, 0);

        // 4) lds-only barrier (vmcnt NOT drained); 5) roll prefetch regs
        barrier_lds_only();
        if (kk + 2 < NK) {
            #pragma unroll
            for (int i = 0; i < 4; ++i) { aP[i] = aN[i]; bP[i] = bN[i]; }
        }
    }

    const int fq = lane >> 4;
    #pragma unroll
    for (int n = 0; n < 4; ++n) {
        const long col = colB + wc + n*16 + fr;
        const float bn = HAS_BIAS ? bias[col] : 0.0f;
        #pragma unroll
        for (int m = 0; m < 4; ++m) {
            const long row0 = rowA + wr + m*16 + fq*4;
            #pragma unroll
            for (int j = 0; j < 4; ++j) {
                float x = acc[m][n][j] + bn;
                if (ACT == 1) x = fmaxf(x, 0.0f);
                Cz[(row0 + j) * (long)ldc + col] = x;
            }
        }
    }
}

// ---------------- GAT1 attention (round-14 verbatim) -------------------------
__global__ __launch_bounds__(256)
void gat1_attn_kernel(float* __restrict__ h1,
                      const int* __restrict__ missing,
                      const float* __restrict__ attl, const float* __restrict__ attr,
                      const float* __restrict__ bias)
{
    const int gtid = blockIdx.x * 256 + threadIdx.x;
    const int wid  = gtid >> 6;
    const int lane = threadIdx.x & 63;
    const int b = wid >> 2;
    const int h = wid & 3;
    const int cb = h * 128 + lane;
    float* base = h1 + (size_t)b * 2048 + cb;

    float hr[4][2];
    #pragma unroll
    for (int j = 0; j < 4; ++j) { hr[j][0] = base[j*512]; hr[j][1] = base[j*512 + 64]; }
    const float al0 = attl[cb], al1 = attl[cb+64];
    const float ar0 = attr[cb], ar1 = attr[cb+64];

    float red[18];
    #pragma unroll
    for (int i = 0; i < 4; ++i)
        #pragma unroll
        for (int j = i; j < 4; ++j)
            red[SYM(i,j)] = hr[i][0]*hr[j][0] + hr[i][1]*hr[j][1];
    #pragma unroll
    for (int j = 0; j < 4; ++j) {
        red[10+j] = hr[j][0]*al0 + hr[j][1]*al1;
        red[14+j] = hr[j][0]*ar0 + hr[j][1]*ar1;
    }
    #pragma unroll
    for (int m = 1; m < 64; m <<= 1)
        #pragma unroll
        for (int r = 0; r < 18; ++r)
            red[r] += __shfl_xor(red[r], m, 64);

    const int miss = missing[b];
    bool pres[4];
    #pragma unroll
    for (int mm = 0; mm < 4; ++mm) pres[mm] = (miss != mm + 1);

    float attn[4][4];
    #pragma unroll
    for (int i = 0; i < 4; ++i) {
        float av[4]; float mx = -3.4e38f;
        #pragma unroll
        for (int j = 0; j < 4; ++j) {
            const bool mk = (i == j) || (pres[i] && pres[j]);
            const float l = (i <= j) ? red[SYM(i,j)] : red[SYM(j,i)];
            float v = (red[14+i] + red[10+j]) * sigmoidf_(l);
            v = (v >= 0.0f) ? v : 0.2f * v;
            av[j] = mk ? v : -1e30f;
            mx = fmaxf(mx, av[j]);
        }
        float den = 0.0f;
        #pragma unroll
        for (int j = 0; j < 4; ++j) { av[j] = __expf(av[j] - mx); den += av[j]; }
        const float inv = 1.0f / den;
        #pragma unroll
        for (int j = 0; j < 4; ++j) attn[i][j] = av[j] * inv;
    }

    const float b0 = bias[cb], b1 = bias[cb+64];
    #pragma unroll
    for (int i = 0; i < 4; ++i) {
        float o0 = b0, o1 = b1;
        #pragma unroll
        for (int j = 0; j < 4; ++j) { o0 += attn[i][j]*hr[j][0]; o1 += attn[i][j]*hr[j][1]; }
        base[i*512]      = gelu_(o0);
        base[i*512 + 64] = gelu_(o1);
    }
}

// ------- GAT2 attention + pool + LayerNorm (round-14 verbatim) ---------------
__global__ __launch_bounds__(256)
void gat2_attn_kernel(const float* __restrict__ h2,
                      const int* __restrict__ missing,
                      const float* __restrict__ attl, const float* __restrict__ attr,
                      const float* __restrict__ bias,
                      const float* __restrict__ lng, const float* __restrict__ lnb,
                      float* __restrict__ normed)
{
    const int gtid = blockIdx.x * 256 + threadIdx.x;
    const int b = gtid >> 6;
    const int lane = threadIdx.x & 63;
    const float4* hp = (const float4*)(h2 + (size_t)b * 1024);

    float4 hr[4];
    #pragma unroll
    for (int j = 0; j < 4; ++j) hr[j] = hp[j*64 + lane];
    const float4 al = ((const float4*)attl)[lane];
    const float4 ar = ((const float4*)attr)[lane];

    float red[18];
    #pragma unroll
    for (int i = 0; i < 4; ++i)
        #pragma unroll
        for (int j = i; j < 4; ++j)
            red[SYM(i,j)] = hr[i].x*hr[j].x + hr[i].y*hr[j].y + hr[i].z*hr[j].z + hr[i].w*hr[j].w;
    #pragma unroll
    for (int j = 0; j < 4; ++j) {
        red[10+j] = hr[j].x*al.x + hr[j].y*al.y + hr[j].z*al.z + hr[j].w*al.w;
        red[14+j] = hr[j].x*ar.x + hr[j].y*ar.y + hr[j].z*ar.z + hr[j].w*ar.w;
    }
    #pragma unroll
    for (int m = 1; m < 64; m <<= 1)
        #pragma unroll
        for (int r = 0; r < 18; ++r)
            red[r] += __shfl_xor(red[r], m, 64);

    const int miss = missing[b];
    bool pres[4];
    #pragma unroll
    for (int mm = 0; mm < 4; ++mm) pres[mm] = (miss != mm + 1);

    float wsum[4] = {0.f, 0.f, 0.f, 0.f};
    #pragma unroll
    for (int i = 0; i < 4; ++i) {
        float av[4]; float mx = -3.4e38f;
        #pragma unroll
        for (int j = 0; j < 4; ++j) {
            const bool mk = (i == j) || (pres[i] && pres[j]);
            const float l = (i <= j) ? red[SYM(i,j)] : red[SYM(j,i)];
            float v = (red[14+i] + red[10+j]) * sigmoidf_(l);
            v = (v >= 0.0f) ? v : 0.2f * v;
            av[j] = mk ? v : -1e30f;
            mx = fmaxf(mx, av[j]);
        }
        float den = 0.0f;
        #pragma unroll
        for (int j = 0; j < 4; ++j) { av[j] = __expf(av[j] - mx); den += av[j]; }
        const float inv = 0.25f / den;
        #pragma unroll
        for (int j = 0; j < 4; ++j) wsum[j] += av[j] * inv;
    }

    const float4 bv = ((const float4*)bias)[lane];
    float pooled[4] = {bv.x, bv.y, bv.z, bv.w};
    #pragma unroll
    for (int j = 0; j < 4; ++j) {
        pooled[0] += wsum[j] * hr[j].x;
        pooled[1] += wsum[j] * hr[j].y;
        pooled[2] += wsum[j] * hr[j].z;
        pooled[3] += wsum[j] * hr[j].w;
    }

    float s1 = pooled[0] + pooled[1] + pooled[2] + pooled[3];
    float s2 = pooled[0]*pooled[0] + pooled[1]*pooled[1] + pooled[2]*pooled[2] + pooled[3]*pooled[3];
    #pragma unroll
    for (int m = 1; m < 64; m <<= 1) {
        s1 += __shfl_xor(s1, m, 64);
        s2 += __shfl_xor(s2, m, 64);
    }
    const float mu   = s1 * (1.0f / 256.0f);
    const float var  = s2 * (1.0f / 256.0f) - mu * mu;
    const float rstd = rsqrtf(var + 1e-5f);
    const float4 g  = ((const float4*)lng)[lane];
    const float4 bb = ((const float4*)lnb)[lane];
    float4 o;
    o.x = (pooled[0] - mu) * rstd * g.x + bb.x;
    o.y = (pooled[1] - mu) * rstd * g.y + bb.y;
    o.z = (pooled[2] - mu) * rstd * g.z + bb.z;
    o.w = (pooled[3] - mu) * rstd * g.w + bb.w;
    ((float4*)normed)[(size_t)b * 64 + lane] = o;
}

// ---------------- head2 (round-4 verbatim) ----------------------------------
__global__ __launch_bounds__(256)
void head2_kernel(const float* __restrict__ hid, const float* __restrict__ W2,
                  const float* __restrict__ b2, float* __restrict__ out)
{
    const int t = blockIdx.x * 256 + threadIdx.x;
    const int b = t >> 3, o = t & 7;
    const float4* hp = (const float4*)(hid + (size_t)b * 256);
    const float4* wp = (const float4*)(W2 + o * 256);
    float acc = b2[o];
    #pragma unroll 8
    for (int c = 0; c < 64; ++c) {
        const float4 hv = hp[c], wv = wp[c];
        acc += hv.x*wv.x + hv.y*wv.y + hv.z*wv.z + hv.w*wv.w;
    }
    out[t] = acc;
}

// ---------------- launch (round-4/14 verbatim) -------------------------------
extern "C" void kernel_launch(void* const* d_in, const int* in_sizes, int n_in,
                              void* d_out, int out_size, void* d_ws, size_t ws_size,
                              hipStream_t stream)
{
    (void)in_sizes; (void)n_in; (void)out_size; (void)ws_size;
    const float* X0 = (const float*)d_in[0];
    const float* X1 = (const float*)d_in[1];
    const float* X2 = (const float*)d_in[2];
    const float* X3 = (const float*)d_in[3];
    const int*   miss  = (const int*)d_in[4];
    const float* g1_W  = (const float*)d_in[13];
    const float* g1_al = (const float*)d_in[14];
    const float* g1_ar = (const float*)d_in[15];
    const float* g1_b  = (const float*)d_in[16];
    const float* g2_W  = (const float*)d_in[17];
    const float* g2_al = (const float*)d_in[18];
    const float* g2_ar = (const float*)d_in[19];
    const float* g2_b  = (const float*)d_in[20];
    const float* ln_g  = (const float*)d_in[21];
    const float* ln_b  = (const float*)d_in[22];
    const float* h_W1  = (const float*)d_in[23];
    const float* h_b1  = (const float*)d_in[24];
    const float* h_W2  = (const float*)d_in[25];
    const float* h_b2  = (const float*)d_in[26];
    float* out = (float*)d_out;

    float* ws     = (float*)d_ws;
    float* feats  = ws;
    float* h1     = ws + 16777216;
    float* h2     = ws;
    float* normed = ws + 16777216;
    float* hid    = normed + 4194304;

    const dim3 blk(256);

    P4 Xs  = {{X0, X1, X2, X3}};
    P4 Wms = {{(const float*)d_in[5], (const float*)d_in[7],
               (const float*)d_in[9], (const float*)d_in[11]}};
    P4 bms = {{(const float*)d_in[6], (const float*)d_in[8],
               (const float*)d_in[10], (const float*)d_in[12]}};
    P4 F4  = {{feats, feats, feats, feats}};
    P4 G1W = {{g1_W, g1_W, g1_W, g1_W}};
    P4 H14 = {{h1, h1, h1, h1}};
    P4 G2W = {{g2_W, g2_W, g2_W, g2_W}};
    P4 N4  = {{normed, normed, normed, normed}};
    P4 HW1 = {{h_W1, h_W1, h_W1, h_W1}};
    P4 HB1 = {{h_b1, h_b1, h_b1, h_b1}};
    P4 NUL = {{nullptr, nullptr, nullptr, nullptr}};

    // 1) per-modality projections (z-batched): feats[B,4,256]
    gemm_nt_mfma<0, true><<<dim3(2, 128, 4), blk, 0, stream>>>(
        Xs, Wms, bms, feats, /*K=*/1024, /*lda=*/1024, /*ldc=*/1024, /*zofs=*/256);

    // 2) gat1 linear: h1[65536,512] = feats[65536,256] @ g1_W^T
    gemm_nt_mfma<0, false><<<dim3(4, 512, 1), blk, 0, stream>>>(
        F4, G1W, NUL, h1, 256, 256, 512, 0);

    // 3) gat1 attention + bias + gelu (in-place on h1)
    gat1_attn_kernel<<<dim3(16384), blk, 0, stream>>>(h1, miss, g1_al, g1_ar, g1_b);

    // 4) gat2 linear: h2[65536,256] = x1[65536,512] @ g2_W^T
    gemm_nt_mfma<0, false><<<dim3(2, 512, 1), blk, 0, stream>>>(
        H14, G2W, NUL, h2, 512, 512, 256, 0);

    // 5) gat2 attention + pool + layernorm -> normed[16384,256]
    gat2_attn_kernel<<<dim3(4096), blk, 0, stream>>>(
        h2, miss, g2_al, g2_ar, g2_b, ln_g, ln_b, normed);

    // 6) head1: hid = relu(normed @ h_W1^T + h_b1)
    gemm_nt_mfma<1, true><<<dim3(2, 128, 1), blk, 0, stream>>>(
        N4, HW1, HB1, hid, 256, 256, 256, 0);

    // 7) head2: out[16384,8]
    head2_kernel<<<dim3(512), blk, 0, stream>>>(hid, h_W2, h_b2, out);
}

// Round 18
// 370.718 us; speedup vs baseline: 1.2300x; 1.0189x over previous
//
#include <hip/hip_runtime.h>

// B=16384, FEAT=1024, FD=256, M=4 nodes, H1=4x128 (concat->512), H2=1x256, OUT=8.
// Round 18: r14 base + ONE change: GEMM blocks go 256->512 threads (8 waves,
// 2x4 wave grid) on the SAME 128x128 tile — wave tile 64x32, acc[4][2].
// Doubles waves/CU for latency hiding; staged bytes, tile sizes, per-element
// accumulation chains all unchanged -> bit-identical math.

typedef __attribute__((ext_vector_type(8))) _Float16 f16x8;
typedef __attribute__((ext_vector_type(4))) float f32x4;

struct P4 { const float* p[4]; };

#define SYM(i,j) ((i)*(7-(i))/2 + (j))

__device__ __forceinline__ float sigmoidf_(float x) { return 1.0f / (1.0f + __expf(-x)); }
__device__ __forceinline__ float gelu_(float x) {
    return 0.5f * x * (1.0f + erff(x * 0.70710678118654752440f));
}

// ---------------- fp16-MFMA NT GEMM: 512 threads = 8 waves (2 row x 4 col) ---
// BM=BN=128, BK=32. r13 schedule: dbuf LDS, 2-ahead register prefetch,
// ds_write-at-top, one __syncthreads per iter.
template<int ACT, bool HAS_BIAS>
__global__ __launch_bounds__(512)
void gemm_nt_mfma(P4 A4, P4 W4, P4 b4, float* __restrict__ C,
                  int K, int lda, int ldc, int zofs)
{
    __shared__ __align__(16) _Float16 As[2][128][32];
    __shared__ __align__(16) _Float16 Bs[2][128][32];
    const int z = blockIdx.z;
    const float* __restrict__ A    = A4.p[z];
    const float* __restrict__ Bw   = W4.p[z];
    const float* __restrict__ bias = b4.p[z];
    float* __restrict__ Cz = C + (long)z * zofs;

    const int t    = threadIdx.x;          // 0..511
    const int lane = t & 63;
    const int w    = t >> 6;               // 0..7
    const int wr   = (w >> 2) << 6;        // wave row base: 0 / 64
    const int wc   = (w & 3) << 5;         // wave col base: 0/32/64/96
    const long rowA = (long)blockIdx.y * 128;
    const long colB = (long)blockIdx.x * 128;

    // staging: slot f = t + i*512 (i=0,1) -> row f>>3 (0..127), col (f&7)*4
    const float* Apt[2];
    const float* Bpt[2];
    int rr[2], cc[2];
    #pragma unroll
    for (int i = 0; i < 2; ++i) {
        const int f = t + i * 512;
        rr[i] = f >> 3;
        cc[i] = (f & 7) << 2;
        Apt[i] = A  + (rowA + rr[i]) * (long)lda + cc[i];
        Bpt[i] = Bw + (colB + rr[i]) * (long)K   + cc[i];
    }

    f32x4 acc[4][2] = {};
    const int NK = K >> 5;

    // prologue: tile 0 -> LDS buf0; tile 1 -> regs
    float4 aP[2], bP[2], aN[2], bN[2];
    #pragma unroll
    for (int i = 0; i < 2; ++i) {
        aP[i] = *(const float4*)(Apt[i]);
        bP[i] = *(const float4*)(Bpt[i]);
    }
    #pragma unroll
    for (int i = 0; i < 2; ++i) {
        union { _Float16 h[4]; uint2 u; } pa, pb;
        pa.h[0] = (_Float16)aP[i].x; pa.h[1] = (_Float16)aP[i].y;
        pa.h[2] = (_Float16)aP[i].z; pa.h[3] = (_Float16)aP[i].w;
        pb.h[0] = (_Float16)bP[i].x; pb.h[1] = (_Float16)bP[i].y;
        pb.h[2] = (_Float16)bP[i].z; pb.h[3] = (_Float16)bP[i].w;
        *(uint2*)&As[0][rr[i]][cc[i]] = pa.u;
        *(uint2*)&Bs[0][rr[i]][cc[i]] = pb.u;
    }
    if (NK > 1) {
        #pragma unroll
        for (int i = 0; i < 2; ++i) {
            aP[i] = *(const float4*)(Apt[i] + 32);
            bP[i] = *(const float4*)(Bpt[i] + 32);
        }
    }
    __syncthreads();

    const int fr = lane & 15;
    const int fg = (lane >> 4) << 3;

    for (int kk = 0; kk < NK; ++kk) {
        const int cur = kk & 1, nxt = cur ^ 1;

        // 1) write tile kk+1 (regs loaded a full iteration ago) -> buf[nxt]
        if (kk + 1 < NK) {
            #pragma unroll
            for (int i = 0; i < 2; ++i) {
                union { _Float16 h[4]; uint2 u; } pa, pb;
                pa.h[0] = (_Float16)aP[i].x; pa.h[1] = (_Float16)aP[i].y;
                pa.h[2] = (_Float16)aP[i].z; pa.h[3] = (_Float16)aP[i].w;
                pb.h[0] = (_Float16)bP[i].x; pb.h[1] = (_Float16)bP[i].y;
                pb.h[2] = (_Float16)bP[i].z; pb.h[3] = (_Float16)bP[i].w;
                *(uint2*)&As[nxt][rr[i]][cc[i]] = pa.u;
                *(uint2*)&Bs[nxt][rr[i]][cc[i]] = pb.u;
            }
        }

        // 2) issue loads for tile kk+2
        if (kk + 2 < NK) {
            const int ko = (kk + 2) << 5;
            #pragma unroll
            for (int i = 0; i < 2; ++i) {
                aN[i] = *(const float4*)(Apt[i] + ko);
                bN[i] = *(const float4*)(Bpt[i] + ko);
            }
        }

        // 3) fragments + MFMA on buf[cur]  (4x2 per wave)
        f16x8 af[4], bf[2];
        #pragma unroll
        for (int m = 0; m < 4; ++m) af[m] = *(const f16x8*)&As[cur][wr + m*16 + fr][fg];
        #pragma unroll
        for (int n = 0; n < 2; ++n) bf[n] = *(const f16x8*)&Bs[cur][wc + n*16 + fr][fg];
        #pragma unroll
        for (int m = 0; m < 4; ++m)
            #pragma unroll
            for (int n = 0; n < 2; ++n)
                acc[m][n] = __builtin_amdgcn_mfma_f32_16x16x32_f16(af[m], bf[n], acc[m][n], 0, 0, 0);

        // 4) barrier; 5) roll prefetch regs
        __syncthreads();
        if (kk + 2 < NK) {
            #pragma unroll
            for (int i = 0; i < 2; ++i) { aP[i] = aN[i]; bP[i] = bN[i]; }
        }
    }

    // ---- epilogue: col = lane&15, row = (lane>>4)*4 + j ----
    const int fq = lane >> 4;
    #pragma unroll
    for (int n = 0; n < 2; ++n) {
        const long col = colB + wc + n*16 + fr;
        const float bn = HAS_BIAS ? bias[col] : 0.0f;
        #pragma unroll
        for (int m = 0; m < 4; ++m) {
            const long row0 = rowA + wr + m*16 + fq*4;
            #pragma unroll
            for (int j = 0; j < 4; ++j) {
                float x = acc[m][n][j] + bn;
                if (ACT == 1) x = fmaxf(x, 0.0f);
                Cz[(row0 + j) * (long)ldc + col] = x;
            }
        }
    }
}

// ---------------- GAT1 attention (round-14 verbatim) -------------------------
__global__ __launch_bounds__(256)
void gat1_attn_kernel(float* __restrict__ h1,
                      const int* __restrict__ missing,
                      const float* __restrict__ attl, const float* __restrict__ attr,
                      const float* __restrict__ bias)
{
    const int gtid = blockIdx.x * 256 + threadIdx.x;
    const int wid  = gtid >> 6;
    const int lane = threadIdx.x & 63;
    const int b = wid >> 2;
    const int h = wid & 3;
    const int cb = h * 128 + lane;
    float* base = h1 + (size_t)b * 2048 + cb;

    float hr[4][2];
    #pragma unroll
    for (int j = 0; j < 4; ++j) { hr[j][0] = base[j*512]; hr[j][1] = base[j*512 + 64]; }
    const float al0 = attl[cb], al1 = attl[cb+64];
    const float ar0 = attr[cb], ar1 = attr[cb+64];

    float red[18];
    #pragma unroll
    for (int i = 0; i < 4; ++i)
        #pragma unroll
        for (int j = i; j < 4; ++j)
            red[SYM(i,j)] = hr[i][0]*hr[j][0] + hr[i][1]*hr[j][1];
    #pragma unroll
    for (int j = 0; j < 4; ++j) {
        red[10+j] = hr[j][0]*al0 + hr[j][1]*al1;
        red[14+j] = hr[j][0]*ar0 + hr[j][1]*ar1;
    }
    #pragma unroll
    for (int m = 1; m < 64; m <<= 1)
        #pragma unroll
        for (int r = 0; r < 18; ++r)
            red[r] += __shfl_xor(red[r], m, 64);

    const int miss = missing[b];
    bool pres[4];
    #pragma unroll
    for (int mm = 0; mm < 4; ++mm) pres[mm] = (miss != mm + 1);

    float attn[4][4];
    #pragma unroll
    for (int i = 0; i < 4; ++i) {
        float av[4]; float mx = -3.4e38f;
        #pragma unroll
        for (int j = 0; j < 4; ++j) {
            const bool mk = (i == j) || (pres[i] && pres[j]);
            const float l = (i <= j) ? red[SYM(i,j)] : red[SYM(j,i)];
            float v = (red[14+i] + red[10+j]) * sigmoidf_(l);
            v = (v >= 0.0f) ? v : 0.2f * v;
            av[j] = mk ? v : -1e30f;
            mx = fmaxf(mx, av[j]);
        }
        float den = 0.0f;
        #pragma unroll
        for (int j = 0; j < 4; ++j) { av[j] = __expf(av[j] - mx); den += av[j]; }
        const float inv = 1.0f / den;
        #pragma unroll
        for (int j = 0; j < 4; ++j) attn[i][j] = av[j] * inv;
    }

    const float b0 = bias[cb], b1 = bias[cb+64];
    #pragma unroll
    for (int i = 0; i < 4; ++i) {
        float o0 = b0, o1 = b1;
        #pragma unroll
        for (int j = 0; j < 4; ++j) { o0 += attn[i][j]*hr[j][0]; o1 += attn[i][j]*hr[j][1]; }
        base[i*512]      = gelu_(o0);
        base[i*512 + 64] = gelu_(o1);
    }
}

// ------- GAT2 attention + pool + LayerNorm (round-14 verbatim) ---------------
__global__ __launch_bounds__(256)
void gat2_attn_kernel(const float* __restrict__ h2,
                      const int* __restrict__ missing,
                      const float* __restrict__ attl, const float* __restrict__ attr,
                      const float* __restrict__ bias,
                      const float* __restrict__ lng, const float* __restrict__ lnb,
                      float* __restrict__ normed)
{
    const int gtid = blockIdx.x * 256 + threadIdx.x;
    const int b = gtid >> 6;
    const int lane = threadIdx.x & 63;
    const float4* hp = (const float4*)(h2 + (size_t)b * 1024);

    float4 hr[4];
    #pragma unroll
    for (int j = 0; j < 4; ++j) hr[j] = hp[j*64 + lane];
    const float4 al = ((const float4*)attl)[lane];
    const float4 ar = ((const float4*)attr)[lane];

    float red[18];
    #pragma unroll
    for (int i = 0; i < 4; ++i)
        #pragma unroll
        for (int j = i; j < 4; ++j)
            red[SYM(i,j)] = hr[i].x*hr[j].x + hr[i].y*hr[j].y + hr[i].z*hr[j].z + hr[i].w*hr[j].w;
    #pragma unroll
    for (int j = 0; j < 4; ++j) {
        red[10+j] = hr[j].x*al.x + hr[j].y*al.y + hr[j].z*al.z + hr[j].w*al.w;
        red[14+j] = hr[j].x*ar.x + hr[j].y*ar.y + hr[j].z*ar.z + hr[j].w*ar.w;
    }
    #pragma unroll
    for (int m = 1; m < 64; m <<= 1)
        #pragma unroll
        for (int r = 0; r < 18; ++r)
            red[r] += __shfl_xor(red[r], m, 64);

    const int miss = missing[b];
    bool pres[4];
    #pragma unroll
    for (int mm = 0; mm < 4; ++mm) pres[mm] = (miss != mm + 1);

    float wsum[4] = {0.f, 0.f, 0.f, 0.f};
    #pragma unroll
    for (int i = 0; i < 4; ++i) {
        float av[4]; float mx = -3.4e38f;
        #pragma unroll
        for (int j = 0; j < 4; ++j) {
            const bool mk = (i == j) || (pres[i] && pres[j]);
            const float l = (i <= j) ? red[SYM(i,j)] : red[SYM(j,i)];
            float v = (red[14+i] + red[10+j]) * sigmoidf_(l);
            v = (v >= 0.0f) ? v : 0.2f * v;
            av[j] = mk ? v : -1e30f;
            mx = fmaxf(mx, av[j]);
        }
        float den = 0.0f;
        #pragma unroll
        for (int j = 0; j < 4; ++j) { av[j] = __expf(av[j] - mx); den += av[j]; }
        const float inv = 0.25f / den;
        #pragma unroll
        for (int j = 0; j < 4; ++j) wsum[j] += av[j] * inv;
    }

    const float4 bv = ((const float4*)bias)[lane];
    float pooled[4] = {bv.x, bv.y, bv.z, bv.w};
    #pragma unroll
    for (int j = 0; j < 4; ++j) {
        pooled[0] += wsum[j] * hr[j].x;
        pooled[1] += wsum[j] * hr[j].y;
        pooled[2] += wsum[j] * hr[j].z;
        pooled[3] += wsum[j] * hr[j].w;
    }

    float s1 = pooled[0] + pooled[1] + pooled[2] + pooled[3];
    float s2 = pooled[0]*pooled[0] + pooled[1]*pooled[1] + pooled[2]*pooled[2] + pooled[3]*pooled[3];
    #pragma unroll
    for (int m = 1; m < 64; m <<= 1) {
        s1 += __shfl_xor(s1, m, 64);
        s2 += __shfl_xor(s2, m, 64);
    }
    const float mu   = s1 * (1.0f / 256.0f);
    const float var  = s2 * (1.0f / 256.0f) - mu * mu;
    const float rstd = rsqrtf(var + 1e-5f);
    const float4 g  = ((const float4*)lng)[lane];
    const float4 bb = ((const float4*)lnb)[lane];
    float4 o;
    o.x = (pooled[0] - mu) * rstd * g.x + bb.x;
    o.y = (pooled[1] - mu) * rstd * g.y + bb.y;
    o.z = (pooled[2] - mu) * rstd * g.z + bb.z;
    o.w = (pooled[3] - mu) * rstd * g.w + bb.w;
    ((float4*)normed)[(size_t)b * 64 + lane] = o;
}

// ---------------- head2 (round-4 verbatim) ----------------------------------
__global__ __launch_bounds__(256)
void head2_kernel(const float* __restrict__ hid, const float* __restrict__ W2,
                  const float* __restrict__ b2, float* __restrict__ out)
{
    const int t = blockIdx.x * 256 + threadIdx.x;
    const int b = t >> 3, o = t & 7;
    const float4* hp = (const float4*)(hid + (size_t)b * 256);
    const float4* wp = (const float4*)(W2 + o * 256);
    float acc = b2[o];
    #pragma unroll 8
    for (int c = 0; c < 64; ++c) {
        const float4 hv = hp[c], wv = wp[c];
        acc += hv.x*wv.x + hv.y*wv.y + hv.z*wv.z + hv.w*wv.w;
    }
    out[t] = acc;
}

// ---------------- launch ----------------------------------------------------
extern "C" void kernel_launch(void* const* d_in, const int* in_sizes, int n_in,
                              void* d_out, int out_size, void* d_ws, size_t ws_size,
                              hipStream_t stream)
{
    (void)in_sizes; (void)n_in; (void)out_size; (void)ws_size;
    const float* X0 = (const float*)d_in[0];
    const float* X1 = (const float*)d_in[1];
    const float* X2 = (const float*)d_in[2];
    const float* X3 = (const float*)d_in[3];
    const int*   miss  = (const int*)d_in[4];
    const float* g1_W  = (const float*)d_in[13];
    const float* g1_al = (const float*)d_in[14];
    const float* g1_ar = (const float*)d_in[15];
    const float* g1_b  = (const float*)d_in[16];
    const float* g2_W  = (const float*)d_in[17];
    const float* g2_al = (const float*)d_in[18];
    const float* g2_ar = (const float*)d_in[19];
    const float* g2_b  = (const float*)d_in[20];
    const float* ln_g  = (const float*)d_in[21];
    const float* ln_b  = (const float*)d_in[22];
    const float* h_W1  = (const float*)d_in[23];
    const float* h_b1  = (const float*)d_in[24];
    const float* h_W2  = (const float*)d_in[25];
    const float* h_b2  = (const float*)d_in[26];
    float* out = (float*)d_out;

    float* ws     = (float*)d_ws;
    float* feats  = ws;
    float* h1     = ws + 16777216;
    float* h2     = ws;
    float* normed = ws + 16777216;
    float* hid    = normed + 4194304;

    const dim3 blkG(512);
    const dim3 blk(256);

    P4 Xs  = {{X0, X1, X2, X3}};
    P4 Wms = {{(const float*)d_in[5], (const float*)d_in[7],
               (const float*)d_in[9], (const float*)d_in[11]}};
    P4 bms = {{(const float*)d_in[6], (const float*)d_in[8],
               (const float*)d_in[10], (const float*)d_in[12]}};
    P4 F4  = {{feats, feats, feats, feats}};
    P4 G1W = {{g1_W, g1_W, g1_W, g1_W}};
    P4 H14 = {{h1, h1, h1, h1}};
    P4 G2W = {{g2_W, g2_W, g2_W, g2_W}};
    P4 N4  = {{normed, normed, normed, normed}};
    P4 HW1 = {{h_W1, h_W1, h_W1, h_W1}};
    P4 HB1 = {{h_b1, h_b1, h_b1, h_b1}};
    P4 NUL = {{nullptr, nullptr, nullptr, nullptr}};

    // 1) per-modality projections (z-batched): feats[B,4,256]
    gemm_nt_mfma<0, true><<<dim3(2, 128, 4), blkG, 0, stream>>>(
        Xs, Wms, bms, feats, /*K=*/1024, /*lda=*/1024, /*ldc=*/1024, /*zofs=*/256);

    // 2) gat1 linear: h1[65536,512] = feats[65536,256] @ g1_W^T
    gemm_nt_mfma<0, false><<<dim3(4, 512, 1), blkG, 0, stream>>>(
        F4, G1W, NUL, h1, 256, 256, 512, 0);

    // 3) gat1 attention + bias + gelu (in-place on h1)
    gat1_attn_kernel<<<dim3(16384), blk, 0, stream>>>(h1, miss, g1_al, g1_ar, g1_b);

    // 4) gat2 linear: h2[65536,256] = x1[65536,512] @ g2_W^T
    gemm_nt_mfma<0, false><<<dim3(2, 512, 1), blkG, 0, stream>>>(
        H14, G2W, NUL, h2, 512, 512, 256, 0);

    // 5) gat2 attention + pool + layernorm -> normed[16384,256]
    gat2_attn_kernel<<<dim3(4096), blk, 0, stream>>>(
        h2, miss, g2_al, g2_ar, g2_b, ln_g, ln_b, normed);

    // 6) head1: hid = relu(normed @ h_W1^T + h_b1)
    gemm_nt_mfma<1, true><<<dim3(2, 128, 1), blkG, 0, stream>>>(
        N4, HW1, HB1, hid, 256, 256, 256, 0);

    // 7) head2: out[16384,8]
    head2_kernel<<<dim3(512), blk, 0, stream>>>(hid, h_W2, h_b2, out);
}

// Round 20
// 352.063 us; speedup vs baseline: 1.2952x; 1.0530x over previous
//
#include <hip/hip_runtime.h>

// B=16384, FEAT=1024, FD=256, M=4 nodes, H1=4x128 (concat->512), H2=1x256, OUT=8.
// Round 20: r18 base (best passing, 370us) + bit-identical precision placement:
// feats fp16 (r6-validated transpose epilogue), h1x fp16 written by gat1_attn
// (reads fp32 h1raw; store-cast == gat2-lin's staging cast), fp16-A staging in
// the 8-wave GEMM. Every cast is a relocated existing cast -> absmax unchanged.

typedef __attribute__((ext_vector_type(8))) _Float16 f16x8;
typedef __attribute__((ext_vector_type(4))) float f32x4;

struct P4 { const void* p[4]; };

#define SYM(i,j) ((i)*(7-(i))/2 + (j))

__device__ __forceinline__ float sigmoidf_(float x) { return 1.0f / (1.0f + __expf(-x)); }
__device__ __forceinline__ float gelu_(float x) {
    return 0.5f * x * (1.0f + erff(x * 0.70710678118654752440f));
}

// ---- MFMA NT GEMM, 512 threads = 8 waves (2 row x 4 col), BM=BN=128, BK=32 --
// A fp32 (cvt at ds_write) or fp16 (direct); W fp32 (cvt at ds_write);
// C fp32 (scattered, r18) or fp16 (LDS-transpose epilogue, r6 pattern).
// r13/r18 schedule: dbuf LDS, 2-ahead register prefetch, one barrier/iter.
template<int ACT, bool A_F32, bool OUT_F16, bool HAS_BIAS>
__global__ __launch_bounds__(512)
void gemm_h8(P4 A4, P4 W4, P4 b4, void* __restrict__ Cv,
             int K, int lda, int ldc, int zofs)
{
    __shared__ __align__(16) unsigned char smem[32768];
    _Float16 (*As)[128][32] = (_Float16(*)[128][32])smem;            // [2][128][32]
    _Float16 (*Bs)[128][32] = (_Float16(*)[128][32])(smem + 16384);  // [2][128][32]
    _Float16 (*outT)[128]   = (_Float16(*)[128])smem;                // [128][128] alias

    const int z = blockIdx.z;
    const float* __restrict__ bias = (const float*)b4.p[z];
    const float* __restrict__ Bw   = (const float*)W4.p[z];

    const int t    = threadIdx.x;          // 0..511
    const int lane = t & 63;
    const int w    = t >> 6;               // 0..7
    const int wr   = (w >> 2) << 6;        // 0 / 64
    const int wc   = (w & 3) << 5;         // 0/32/64/96
    const long rowA = (long)blockIdx.y * 128;
    const long colB = (long)blockIdx.x * 128;

    // B staging (fp32): slot f = t + i*512 -> row f>>3, col (f&7)*4
    const float* Bpt[2];
    int brr[2], bcc[2];
    #pragma unroll
    for (int i = 0; i < 2; ++i) {
        const int f = t + i * 512;
        brr[i] = f >> 3;
        bcc[i] = (f & 7) << 2;
        Bpt[i] = Bw + (colB + brr[i]) * (long)K + bcc[i];
    }
    // A staging
    const float* Apt32[2]; int arr[2], acc_[2];
    const _Float16* Apt16 = nullptr; int a16r = 0, a16c = 0;
    if constexpr (A_F32) {
        const float* A = (const float*)A4.p[z];
        #pragma unroll
        for (int i = 0; i < 2; ++i) {
            const int f = t + i * 512;
            arr[i] = f >> 3;
            acc_[i] = (f & 7) << 2;
            Apt32[i] = A + (rowA + arr[i]) * (long)lda + acc_[i];
        }
    } else {
        const _Float16* A = (const _Float16*)A4.p[z];
        a16r = t >> 2;                 // 0..127
        a16c = (t & 3) << 3;           // 0,8,16,24 (halves)
        Apt16 = A + (rowA + a16r) * (long)lda + a16c;
    }

    f32x4 acc[4][2] = {};
    const int NK = K >> 5;

    float4 aP32[2], aN32[2], bP[2], bN[2];
    uint4  aP16 = {}, aN16 = {};

    // prologue: tile 0 -> regs -> buf0
    if constexpr (A_F32) {
        #pragma unroll
        for (int i = 0; i < 2; ++i) aP32[i] = *(const float4*)(Apt32[i]);
    } else {
        aP16 = *(const uint4*)(Apt16);
    }
    #pragma unroll
    for (int i = 0; i < 2; ++i) bP[i] = *(const float4*)(Bpt[i]);

    if constexpr (A_F32) {
        #pragma unroll
        for (int i = 0; i < 2; ++i) {
            union { _Float16 h[4]; uint2 u; } pa;
            pa.h[0] = (_Float16)aP32[i].x; pa.h[1] = (_Float16)aP32[i].y;
            pa.h[2] = (_Float16)aP32[i].z; pa.h[3] = (_Float16)aP32[i].w;
            *(uint2*)&As[0][arr[i]][acc_[i]] = pa.u;
        }
    } else {
        *(uint4*)&As[0][a16r][a16c] = aP16;
    }
    #pragma unroll
    for (int i = 0; i < 2; ++i) {
        union { _Float16 h[4]; uint2 u; } pb;
        pb.h[0] = (_Float16)bP[i].x; pb.h[1] = (_Float16)bP[i].y;
        pb.h[2] = (_Float16)bP[i].z; pb.h[3] = (_Float16)bP[i].w;
        *(uint2*)&Bs[0][brr[i]][bcc[i]] = pb.u;
    }
    // tile 1 -> regs
    if (NK > 1) {
        if constexpr (A_F32) {
            #pragma unroll
            for (int i = 0; i < 2; ++i) aP32[i] = *(const float4*)(Apt32[i] + 32);
        } else {
            aP16 = *(const uint4*)(Apt16 + 32);
        }
        #pragma unroll
        for (int i = 0; i < 2; ++i) bP[i] = *(const float4*)(Bpt[i] + 32);
    }
    __syncthreads();

    const int fr = lane & 15;
    const int fq = lane >> 4;
    const int fg = fq << 3;

    for (int kk = 0; kk < NK; ++kk) {
        const int cur = kk & 1, nxt = cur ^ 1;

        // 1) ds_write tile kk+1 (regs loaded a full iteration ago)
        if (kk + 1 < NK) {
            if constexpr (A_F32) {
                #pragma unroll
                for (int i = 0; i < 2; ++i) {
                    union { _Float16 h[4]; uint2 u; } pa;
                    pa.h[0] = (_Float16)aP32[i].x; pa.h[1] = (_Float16)aP32[i].y;
                    pa.h[2] = (_Float16)aP32[i].z; pa.h[3] = (_Float16)aP32[i].w;
                    *(uint2*)&As[nxt][arr[i]][acc_[i]] = pa.u;
                }
            } else {
                *(uint4*)&As[nxt][a16r][a16c] = aP16;
            }
            #pragma unroll
            for (int i = 0; i < 2; ++i) {
                union { _Float16 h[4]; uint2 u; } pb;
                pb.h[0] = (_Float16)bP[i].x; pb.h[1] = (_Float16)bP[i].y;
                pb.h[2] = (_Float16)bP[i].z; pb.h[3] = (_Float16)bP[i].w;
                *(uint2*)&Bs[nxt][brr[i]][bcc[i]] = pb.u;
            }
        }

        // 2) issue loads for tile kk+2
        if (kk + 2 < NK) {
            const int ko = (kk + 2) << 5;
            if constexpr (A_F32) {
                #pragma unroll
                for (int i = 0; i < 2; ++i) aN32[i] = *(const float4*)(Apt32[i] + ko);
            } else {
                aN16 = *(const uint4*)(Apt16 + ko);
            }
            #pragma unroll
            for (int i = 0; i < 2; ++i) bN[i] = *(const float4*)(Bpt[i] + ko);
        }

        // 3) fragments + MFMA on buf[cur]
        f16x8 af[4], bf[2];
        #pragma unroll
        for (int m = 0; m < 4; ++m) af[m] = *(const f16x8*)&As[cur][wr + m*16 + fr][fg];
        #pragma unroll
        for (int n = 0; n < 2; ++n) bf[n] = *(const f16x8*)&Bs[cur][wc + n*16 + fr][fg];
        #pragma unroll
        for (int m = 0; m < 4; ++m)
            #pragma unroll
            for (int n = 0; n < 2; ++n)
                acc[m][n] = __builtin_amdgcn_mfma_f32_16x16x32_f16(af[m], bf[n], acc[m][n], 0, 0, 0);

        // 4) barrier; 5) roll prefetch regs
        __syncthreads();
        if (kk + 2 < NK) {
            if constexpr (A_F32) {
                #pragma unroll
                for (int i = 0; i < 2; ++i) aP32[i] = aN32[i];
            } else {
                aP16 = aN16;
            }
            #pragma unroll
            for (int i = 0; i < 2; ++i) bP[i] = bN[i];
        }
    }

    if constexpr (OUT_F16) {
        _Float16* Cz = (_Float16*)Cv + (long)z * zofs;
        __syncthreads();   // all frag reads done; outT aliases staging
        float bn[2];
        #pragma unroll
        for (int n = 0; n < 2; ++n)
            bn[n] = HAS_BIAS ? bias[colB + wc + n*16 + fr] : 0.0f;
        #pragma unroll
        for (int m = 0; m < 4; ++m)
            #pragma unroll
            for (int n = 0; n < 2; ++n)
                #pragma unroll
                for (int j = 0; j < 4; ++j) {
                    float x = acc[m][n][j] + bn[n];
                    if (ACT == 1) x = fmaxf(x, 0.0f);
                    outT[wr + m*16 + fq*4 + j][wc + n*16 + fr] = (_Float16)x;
                }
        __syncthreads();
        #pragma unroll
        for (int i = 0; i < 4; ++i) {
            const int s = t + i * 512;
            const int r = s >> 4, c = (s & 15) << 3;
            *(uint4*)(Cz + (rowA + r) * (long)ldc + colB + c) = *(const uint4*)&outT[r][c];
        }
    } else {
        float* Cz = (float*)Cv + (long)z * zofs;
        #pragma unroll
        for (int n = 0; n < 2; ++n) {
            const long col = colB + wc + n*16 + fr;
            const float bn = HAS_BIAS ? bias[col] : 0.0f;
            #pragma unroll
            for (int m = 0; m < 4; ++m) {
                const long row0 = rowA + wr + m*16 + fq*4;
                #pragma unroll
                for (int j = 0; j < 4; ++j) {
                    float x = acc[m][n][j] + bn;
                    if (ACT == 1) x = fmaxf(x, 0.0f);
                    Cz[(row0 + j) * (long)ldc + col] = x;
                }
            }
        }
    }
}

// -- GAT1 attention (r14 math verbatim): reads fp32 h1raw, writes fp16 h1x ----
__global__ __launch_bounds__(256)
void gat1_attn_kernel(const float* __restrict__ h1raw,
                      _Float16* __restrict__ h1x,
                      const int* __restrict__ missing,
                      const float* __restrict__ attl, const float* __restrict__ attr,
                      const float* __restrict__ bias)
{
    const int gtid = blockIdx.x * 256 + threadIdx.x;
    const int wid  = gtid >> 6;
    const int lane = threadIdx.x & 63;
    const int b = wid >> 2;
    const int h = wid & 3;
    const int cb = h * 128 + lane;
    const float* bi = h1raw + (size_t)b * 2048 + cb;
    _Float16*   bo = h1x   + (size_t)b * 2048 + cb;

    float hr[4][2];
    #pragma unroll
    for (int j = 0; j < 4; ++j) { hr[j][0] = bi[j*512]; hr[j][1] = bi[j*512 + 64]; }
    const float al0 = attl[cb], al1 = attl[cb+64];
    const float ar0 = attr[cb], ar1 = attr[cb+64];

    float red[18];
    #pragma unroll
    for (int i = 0; i < 4; ++i)
        #pragma unroll
        for (int j = i; j < 4; ++j)
            red[SYM(i,j)] = hr[i][0]*hr[j][0] + hr[i][1]*hr[j][1];
    #pragma unroll
    for (int j = 0; j < 4; ++j) {
        red[10+j] = hr[j][0]*al0 + hr[j][1]*al1;
        red[14+j] = hr[j][0]*ar0 + hr[j][1]*ar1;
    }
    #pragma unroll
    for (int m = 1; m < 64; m <<= 1)
        #pragma unroll
        for (int r = 0; r < 18; ++r)
            red[r] += __shfl_xor(red[r], m, 64);

    const int miss = missing[b];
    bool pres[4];
    #pragma unroll
    for (int mm = 0; mm < 4; ++mm) pres[mm] = (miss != mm + 1);

    float attn[4][4];
    #pragma unroll
    for (int i = 0; i < 4; ++i) {
        float av[4]; float mx = -3.4e38f;
        #pragma unroll
        for (int j = 0; j < 4; ++j) {
            const bool mk = (i == j) || (pres[i] && pres[j]);
            const float l = (i <= j) ? red[SYM(i,j)] : red[SYM(j,i)];
            float v = (red[14+i] + red[10+j]) * sigmoidf_(l);
            v = (v >= 0.0f) ? v : 0.2f * v;
            av[j] = mk ? v : -1e30f;
            mx = fmaxf(mx, av[j]);
        }
        float den = 0.0f;
        #pragma unroll
        for (int j = 0; j < 4; ++j) { av[j] = __expf(av[j] - mx); den += av[j]; }
        const float inv = 1.0f / den;
        #pragma unroll
        for (int j = 0; j < 4; ++j) attn[i][j] = av[j] * inv;
    }

    const float b0 = bias[cb], b1 = bias[cb+64];
    #pragma unroll
    for (int i = 0; i < 4; ++i) {
        float o0 = b0, o1 = b1;
        #pragma unroll
        for (int j = 0; j < 4; ++j) { o0 += attn[i][j]*hr[j][0]; o1 += attn[i][j]*hr[j][1]; }
        bo[i*512]      = (_Float16)gelu_(o0);   // == gat2-lin's staging cast
        bo[i*512 + 64] = (_Float16)gelu_(o1);
    }
}

// ------- GAT2 attention + pool + LayerNorm (round-14 verbatim) ---------------
__global__ __launch_bounds__(256)
void gat2_attn_kernel(const float* __restrict__ h2,
                      const int* __restrict__ missing,
                      const float* __restrict__ attl, const float* __restrict__ attr,
                      const float* __restrict__ bias,
                      const float* __restrict__ lng, const float* __restrict__ lnb,
                      float* __restrict__ normed)
{
    const int gtid = blockIdx.x * 256 + threadIdx.x;
    const int b = gtid >> 6;
    const int lane = threadIdx.x & 63;
    const float4* hp = (const float4*)(h2 + (size_t)b * 1024);

    float4 hr[4];
    #pragma unroll
    for (int j = 0; j < 4; ++j) hr[j] = hp[j*64 + lane];
    const float4 al = ((const float4*)attl)[lane];
    const float4 ar = ((const float4*)attr)[lane];

    float red[18];
    #pragma unroll
    for (int i = 0; i < 4; ++i)
        #pragma unroll
        for (int j = i; j < 4; ++j)
            red[SYM(i,j)] = hr[i].x*hr[j].x + hr[i].y*hr[j].y + hr[i].z*hr[j].z + hr[i].w*hr[j].w;
    #pragma unroll
    for (int j = 0; j < 4; ++j) {
        red[10+j] = hr[j].x*al.x + hr[j].y*al.y + hr[j].z*al.z + hr[j].w*al.w;
        red[14+j] = hr[j].x*ar.x + hr[j].y*ar.y + hr[j].z*ar.z + hr[j].w*ar.w;
    }
    #pragma unroll
    for (int m = 1; m < 64; m <<= 1)
        #pragma unroll
        for (int r = 0; r < 18; ++r)
            red[r] += __shfl_xor(red[r], m, 64);

    const int miss = missing[b];
    bool pres[4];
    #pragma unroll
    for (int mm = 0; mm < 4; ++mm) pres[mm] = (miss != mm + 1);

    float wsum[4] = {0.f, 0.f, 0.f, 0.f};
    #pragma unroll
    for (int i = 0; i < 4; ++i) {
        float av[4]; float mx = -3.4e38f;
        #pragma unroll
        for (int j = 0; j < 4; ++j) {
            const bool mk = (i == j) || (pres[i] && pres[j]);
            const float l = (i <= j) ? red[SYM(i,j)] : red[SYM(j,i)];
            float v = (red[14+i] + red[10+j]) * sigmoidf_(l);
            v = (v >= 0.0f) ? v : 0.2f * v;
            av[j] = mk ? v : -1e30f;
            mx = fmaxf(mx, av[j]);
        }
        float den = 0.0f;
        #pragma unroll
        for (int j = 0; j < 4; ++j) { av[j] = __expf(av[j] - mx); den += av[j]; }
        const float inv = 0.25f / den;
        #pragma unroll
        for (int j = 0; j < 4; ++j) wsum[j] += av[j] * inv;
    }

    const float4 bv = ((const float4*)bias)[lane];
    float pooled[4] = {bv.x, bv.y, bv.z, bv.w};
    #pragma unroll
    for (int j = 0; j < 4; ++j) {
        pooled[0] += wsum[j] * hr[j].x;
        pooled[1] += wsum[j] * hr[j].y;
        pooled[2] += wsum[j] * hr[j].z;
        pooled[3] += wsum[j] * hr[j].w;
    }

    float s1 = pooled[0] + pooled[1] + pooled[2] + pooled[3];
    float s2 = pooled[0]*pooled[0] + pooled[1]*pooled[1] + pooled[2]*pooled[2] + pooled[3]*pooled[3];
    #pragma unroll
    for (int m = 1; m < 64; m <<= 1) {
        s1 += __shfl_xor(s1, m, 64);
        s2 += __shfl_xor(s2, m, 64);
    }
    const float mu   = s1 * (1.0f / 256.0f);
    const float var  = s2 * (1.0f / 256.0f) - mu * mu;
    const float rstd = rsqrtf(var + 1e-5f);
    const float4 g  = ((const float4*)lng)[lane];
    const float4 bb = ((const float4*)lnb)[lane];
    float4 o;
    o.x = (pooled[0] - mu) * rstd * g.x + bb.x;
    o.y = (pooled[1] - mu) * rstd * g.y + bb.y;
    o.z = (pooled[2] - mu) * rstd * g.z + bb.z;
    o.w = (pooled[3] - mu) * rstd * g.w + bb.w;
    ((float4*)normed)[(size_t)b * 64 + lane] = o;
}

// ---------------- head2 (round-4 verbatim) ----------------------------------
__global__ __launch_bounds__(256)
void head2_kernel(const float* __restrict__ hid, const float* __restrict__ W2,
                  const float* __restrict__ b2, float* __restrict__ out)
{
    const int t = blockIdx.x * 256 + threadIdx.x;
    const int b = t >> 3, o = t & 7;
    const float4* hp = (const float4*)(hid + (size_t)b * 256);
    const float4* wp = (const float4*)(W2 + o * 256);
    float acc = b2[o];
    #pragma unroll 8
    for (int c = 0; c < 64; ++c) {
        const float4 hv = hp[c], wv = wp[c];
        acc += hv.x*wv.x + hv.y*wv.y + hv.z*wv.z + hv.w*wv.w;
    }
    out[t] = acc;
}

// ---------------- launch ----------------------------------------------------
extern "C" void kernel_launch(void* const* d_in, const int* in_sizes, int n_in,
                              void* d_out, int out_size, void* d_ws, size_t ws_size,
                              hipStream_t stream)
{
    (void)in_sizes; (void)n_in; (void)out_size; (void)ws_size;
    const int*   miss  = (const int*)d_in[4];
    const float* g1_al = (const float*)d_in[14];
    const float* g1_ar = (const float*)d_in[15];
    const float* g1_b  = (const float*)d_in[16];
    const float* g2_al = (const float*)d_in[18];
    const float* g2_ar = (const float*)d_in[19];
    const float* g2_b  = (const float*)d_in[20];
    const float* ln_g  = (const float*)d_in[21];
    const float* ln_b  = (const float*)d_in[22];
    const float* h_W2  = (const float*)d_in[25];
    const float* h_b2  = (const float*)d_in[26];
    float* out = (float*)d_out;

    // workspace (MiB offsets; peak 192 MiB = r4-proven footprint):
    //   feats  fp16 [16384,1024] @   0  (32)   -> dead after gat1-lin
    //   h1raw  fp32 [65536,512]  @  64  (128)  -> dead after gat1_attn
    //   h1x    fp16 [65536,512]  @   0  (64)   (overwrites dead feats)
    //   h2     fp32 [65536,256]  @  64  (64)   (overwrites dead h1raw)
    //   normed fp32 [16384,256]  @ 128  (16)
    //   hid    fp32 [16384,256]  @ 144  (16)
    char* base = (char*)d_ws;
    _Float16* feats  = (_Float16*)base;
    float*    h1raw  = (float*)   (base + (64ll  << 20));
    _Float16* h1x    = (_Float16*)base;
    float*    h2     = (float*)   (base + (64ll  << 20));
    float*    normed = (float*)   (base + (128ll << 20));
    float*    hid    = (float*)   (base + (144ll << 20));

    const dim3 blkG(512);
    const dim3 blk(256);

    P4 Xs  = {{d_in[0], d_in[1], d_in[2], d_in[3]}};
    P4 Wms = {{d_in[5], d_in[7], d_in[9], d_in[11]}};
    P4 bms = {{d_in[6], d_in[8], d_in[10], d_in[12]}};
    P4 F4  = {{feats, feats, feats, feats}};
    P4 G1W = {{d_in[13], d_in[13], d_in[13], d_in[13]}};
    P4 H1X = {{h1x, h1x, h1x, h1x}};
    P4 G2W = {{d_in[17], d_in[17], d_in[17], d_in[17]}};
    P4 N4  = {{normed, normed, normed, normed}};
    P4 HW1 = {{d_in[23], d_in[23], d_in[23], d_in[23]}};
    P4 HB1 = {{d_in[24], d_in[24], d_in[24], d_in[24]}};
    P4 NUL = {{nullptr, nullptr, nullptr, nullptr}};

    // 1) projections (z-batched): feats fp16 [16384, 4x256]
    gemm_h8<0, true, true, true><<<dim3(2, 128, 4), blkG, 0, stream>>>(
        Xs, Wms, bms, feats, /*K=*/1024, /*lda=*/1024, /*ldc=*/1024, /*zofs=*/256);

    // 2) gat1 linear: h1raw fp32 [65536,512] = feats(fp16) @ g1_W^T
    gemm_h8<0, false, false, false><<<dim3(4, 512, 1), blkG, 0, stream>>>(
        F4, G1W, NUL, h1raw, 256, 256, 512, 0);

    // 3) gat1 attention + bias + gelu: h1raw fp32 -> h1x fp16
    gat1_attn_kernel<<<dim3(16384), blk, 0, stream>>>(
        h1raw, h1x, miss, g1_al, g1_ar, g1_b);

    // 4) gat2 linear: h2 fp32 [65536,256] = h1x(fp16) @ g2_W^T
    gemm_h8<0, false, false, false><<<dim3(2, 512, 1), blkG, 0, stream>>>(
        H1X, G2W, NUL, h2, 512, 512, 256, 0);

    // 5) gat2 attention + pool + layernorm -> normed fp32
    gat2_attn_kernel<<<dim3(4096), blk, 0, stream>>>(
        h2, miss, g2_al, g2_ar, g2_b, ln_g, ln_b, normed);

    // 6) head1: hid fp32 = relu(normed @ h_W1^T + h_b1)
    gemm_h8<1, true, false, true><<<dim3(2, 128, 1), blkG, 0, stream>>>(
        N4, HW1, HB1, hid, 256, 256, 256, 0);

    // 7) head2: out[16384,8]
    head2_kernel<<<dim3(512), blk, 0, stream>>>(hid, h_W2, h_b2, out);
}

// Round 21
// 343.197 us; speedup vs baseline: 1.3287x; 1.0258x over previous
//
#include <hip/hip_runtime.h>

// B=16384, FEAT=1024, FD=256, M=4 nodes, H1=4x128 (concat->512), H2=1x256, OUT=8.
// Round 21: r20 base (best, 352us) + ONE change: XCD-aware chunked block
// swizzle (bijective, nxy%8==0) applied ONLY to the proj GEMM (X=268MB > L3;
// other GEMM inputs are L3-fit where swizzle costs ~2%). Pure blockIdx remap
// of disjoint outputs -> bit-identical math.

typedef __attribute__((ext_vector_type(8))) _Float16 f16x8;
typedef __attribute__((ext_vector_type(4))) float f32x4;

struct P4 { const void* p[4]; };

#define SYM(i,j) ((i)*(7-(i))/2 + (j))

__device__ __forceinline__ float sigmoidf_(float x) { return 1.0f / (1.0f + __expf(-x)); }
__device__ __forceinline__ float gelu_(float x) {
    return 0.5f * x * (1.0f + erff(x * 0.70710678118654752440f));
}

// ---- MFMA NT GEMM, 512 threads = 8 waves (2 row x 4 col), BM=BN=128, BK=32 --
// A fp32 (cvt at ds_write) or fp16 (direct); W fp32 (cvt at ds_write);
// C fp32 (scattered) or fp16 (LDS-transpose epilogue). r13/r18 schedule.
// SWZ: XCD-aware chunked remap of (bx,by) — each XCD gets a contiguous
// logical range so A-panel-sharing x-pairs co-reside in one L2.
template<int ACT, bool A_F32, bool OUT_F16, bool HAS_BIAS, bool SWZ>
__global__ __launch_bounds__(512)
void gemm_h8(P4 A4, P4 W4, P4 b4, void* __restrict__ Cv,
             int K, int lda, int ldc, int zofs)
{
    __shared__ __align__(16) unsigned char smem[32768];
    _Float16 (*As)[128][32] = (_Float16(*)[128][32])smem;            // [2][128][32]
    _Float16 (*Bs)[128][32] = (_Float16(*)[128][32])(smem + 16384);  // [2][128][32]
    _Float16 (*outT)[128]   = (_Float16(*)[128])smem;                // [128][128] alias

    const int z = blockIdx.z;
    const float* __restrict__ bias = (const float*)b4.p[z];
    const float* __restrict__ Bw   = (const float*)W4.p[z];

    int bx = blockIdx.x, by = blockIdx.y;
    if constexpr (SWZ) {
        const int nxy  = gridDim.x * gridDim.y;      // divisible by 8 (asserted host-side)
        const int flat = by * gridDim.x + bx;        // HW dispatch order (x fastest)
        const int chunk = nxy >> 3;
        const int swz = (flat & 7) * chunk + (flat >> 3);
        bx = swz % gridDim.x;
        by = swz / gridDim.x;
    }

    const int t    = threadIdx.x;          // 0..511
    const int lane = t & 63;
    const int w    = t >> 6;               // 0..7
    const int wr   = (w >> 2) << 6;        // 0 / 64
    const int wc   = (w & 3) << 5;         // 0/32/64/96
    const long rowA = (long)by * 128;
    const long colB = (long)bx * 128;

    // B staging (fp32): slot f = t + i*512 -> row f>>3, col (f&7)*4
    const float* Bpt[2];
    int brr[2], bcc[2];
    #pragma unroll
    for (int i = 0; i < 2; ++i) {
        const int f = t + i * 512;
        brr[i] = f >> 3;
        bcc[i] = (f & 7) << 2;
        Bpt[i] = Bw + (colB + brr[i]) * (long)K + bcc[i];
    }
    // A staging
    const float* Apt32[2]; int arr[2], acc_[2];
    const _Float16* Apt16 = nullptr; int a16r = 0, a16c = 0;
    if constexpr (A_F32) {
        const float* A = (const float*)A4.p[z];
        #pragma unroll
        for (int i = 0; i < 2; ++i) {
            const int f = t + i * 512;
            arr[i] = f >> 3;
            acc_[i] = (f & 7) << 2;
            Apt32[i] = A + (rowA + arr[i]) * (long)lda + acc_[i];
        }
    } else {
        const _Float16* A = (const _Float16*)A4.p[z];
        a16r = t >> 2;                 // 0..127
        a16c = (t & 3) << 3;           // 0,8,16,24 (halves)
        Apt16 = A + (rowA + a16r) * (long)lda + a16c;
    }

    f32x4 acc[4][2] = {};
    const int NK = K >> 5;

    float4 aP32[2], aN32[2], bP[2], bN[2];
    uint4  aP16 = {}, aN16 = {};

    // prologue: tile 0 -> regs -> buf0
    if constexpr (A_F32) {
        #pragma unroll
        for (int i = 0; i < 2; ++i) aP32[i] = *(const float4*)(Apt32[i]);
    } else {
        aP16 = *(const uint4*)(Apt16);
    }
    #pragma unroll
    for (int i = 0; i < 2; ++i) bP[i] = *(const float4*)(Bpt[i]);

    if constexpr (A_F32) {
        #pragma unroll
        for (int i = 0; i < 2; ++i) {
            union { _Float16 h[4]; uint2 u; } pa;
            pa.h[0] = (_Float16)aP32[i].x; pa.h[1] = (_Float16)aP32[i].y;
            pa.h[2] = (_Float16)aP32[i].z; pa.h[3] = (_Float16)aP32[i].w;
            *(uint2*)&As[0][arr[i]][acc_[i]] = pa.u;
        }
    } else {
        *(uint4*)&As[0][a16r][a16c] = aP16;
    }
    #pragma unroll
    for (int i = 0; i < 2; ++i) {
        union { _Float16 h[4]; uint2 u; } pb;
        pb.h[0] = (_Float16)bP[i].x; pb.h[1] = (_Float16)bP[i].y;
        pb.h[2] = (_Float16)bP[i].z; pb.h[3] = (_Float16)bP[i].w;
        *(uint2*)&Bs[0][brr[i]][bcc[i]] = pb.u;
    }
    // tile 1 -> regs
    if (NK > 1) {
        if constexpr (A_F32) {
            #pragma unroll
            for (int i = 0; i < 2; ++i) aP32[i] = *(const float4*)(Apt32[i] + 32);
        } else {
            aP16 = *(const uint4*)(Apt16 + 32);
        }
        #pragma unroll
        for (int i = 0; i < 2; ++i) bP[i] = *(const float4*)(Bpt[i] + 32);
    }
    __syncthreads();

    const int fr = lane & 15;
    const int fq = lane >> 4;
    const int fg = fq << 3;

    for (int kk = 0; kk < NK; ++kk) {
        const int cur = kk & 1, nxt = cur ^ 1;

        // 1) ds_write tile kk+1 (regs loaded a full iteration ago)
        if (kk + 1 < NK) {
            if constexpr (A_F32) {
                #pragma unroll
                for (int i = 0; i < 2; ++i) {
                    union { _Float16 h[4]; uint2 u; } pa;
                    pa.h[0] = (_Float16)aP32[i].x; pa.h[1] = (_Float16)aP32[i].y;
                    pa.h[2] = (_Float16)aP32[i].z; pa.h[3] = (_Float16)aP32[i].w;
                    *(uint2*)&As[nxt][arr[i]][acc_[i]] = pa.u;
                }
            } else {
                *(uint4*)&As[nxt][a16r][a16c] = aP16;
            }
            #pragma unroll
            for (int i = 0; i < 2; ++i) {
                union { _Float16 h[4]; uint2 u; } pb;
                pb.h[0] = (_Float16)bP[i].x; pb.h[1] = (_Float16)bP[i].y;
                pb.h[2] = (_Float16)bP[i].z; pb.h[3] = (_Float16)bP[i].w;
                *(uint2*)&Bs[nxt][brr[i]][bcc[i]] = pb.u;
            }
        }

        // 2) issue loads for tile kk+2
        if (kk + 2 < NK) {
            const int ko = (kk + 2) << 5;
            if constexpr (A_F32) {
                #pragma unroll
                for (int i = 0; i < 2; ++i) aN32[i] = *(const float4*)(Apt32[i] + ko);
            } else {
                aN16 = *(const uint4*)(Apt16 + ko);
            }
            #pragma unroll
            for (int i = 0; i < 2; ++i) bN[i] = *(const float4*)(Bpt[i] + ko);
        }

        // 3) fragments + MFMA on buf[cur]
        f16x8 af[4], bf[2];
        #pragma unroll
        for (int m = 0; m < 4; ++m) af[m] = *(const f16x8*)&As[cur][wr + m*16 + fr][fg];
        #pragma unroll
        for (int n = 0; n < 2; ++n) bf[n] = *(const f16x8*)&Bs[cur][wc + n*16 + fr][fg];
        #pragma unroll
        for (int m = 0; m < 4; ++m)
            #pragma unroll
            for (int n = 0; n < 2; ++n)
                acc[m][n] = __builtin_amdgcn_mfma_f32_16x16x32_f16(af[m], bf[n], acc[m][n], 0, 0, 0);

        // 4) barrier; 5) roll prefetch regs
        __syncthreads();
        if (kk + 2 < NK) {
            if constexpr (A_F32) {
                #pragma unroll
                for (int i = 0; i < 2; ++i) aP32[i] = aN32[i];
            } else {
                aP16 = aN16;
            }
            #pragma unroll
            for (int i = 0; i < 2; ++i) bP[i] = bN[i];
        }
    }

    if constexpr (OUT_F16) {
        _Float16* Cz = (_Float16*)Cv + (long)z * zofs;
        __syncthreads();   // all frag reads done; outT aliases staging
        float bn[2];
        #pragma unroll
        for (int n = 0; n < 2; ++n)
            bn[n] = HAS_BIAS ? bias[colB + wc + n*16 + fr] : 0.0f;
        #pragma unroll
        for (int m = 0; m < 4; ++m)
            #pragma unroll
            for (int n = 0; n < 2; ++n)
                #pragma unroll
                for (int j = 0; j < 4; ++j) {
                    float x = acc[m][n][j] + bn[n];
                    if (ACT == 1) x = fmaxf(x, 0.0f);
                    outT[wr + m*16 + fq*4 + j][wc + n*16 + fr] = (_Float16)x;
                }
        __syncthreads();
        #pragma unroll
        for (int i = 0; i < 4; ++i) {
            const int s = t + i * 512;
            const int r = s >> 4, c = (s & 15) << 3;
            *(uint4*)(Cz + (rowA + r) * (long)ldc + colB + c) = *(const uint4*)&outT[r][c];
        }
    } else {
        float* Cz = (float*)Cv + (long)z * zofs;
        #pragma unroll
        for (int n = 0; n < 2; ++n) {
            const long col = colB + wc + n*16 + fr;
            const float bn = HAS_BIAS ? bias[col] : 0.0f;
            #pragma unroll
            for (int m = 0; m < 4; ++m) {
                const long row0 = rowA + wr + m*16 + fq*4;
                #pragma unroll
                for (int j = 0; j < 4; ++j) {
                    float x = acc[m][n][j] + bn;
                    if (ACT == 1) x = fmaxf(x, 0.0f);
                    Cz[(row0 + j) * (long)ldc + col] = x;
                }
            }
        }
    }
}

// -- GAT1 attention (r20 verbatim): reads fp32 h1raw, writes fp16 h1x ---------
__global__ __launch_bounds__(256)
void gat1_attn_kernel(const float* __restrict__ h1raw,
                      _Float16* __restrict__ h1x,
                      const int* __restrict__ missing,
                      const float* __restrict__ attl, const float* __restrict__ attr,
                      const float* __restrict__ bias)
{
    const int gtid = blockIdx.x * 256 + threadIdx.x;
    const int wid  = gtid >> 6;
    const int lane = threadIdx.x & 63;
    const int b = wid >> 2;
    const int h = wid & 3;
    const int cb = h * 128 + lane;
    const float* bi = h1raw + (size_t)b * 2048 + cb;
    _Float16*   bo = h1x   + (size_t)b * 2048 + cb;

    float hr[4][2];
    #pragma unroll
    for (int j = 0; j < 4; ++j) { hr[j][0] = bi[j*512]; hr[j][1] = bi[j*512 + 64]; }
    const float al0 = attl[cb], al1 = attl[cb+64];
    const float ar0 = attr[cb], ar1 = attr[cb+64];

    float red[18];
    #pragma unroll
    for (int i = 0; i < 4; ++i)
        #pragma unroll
        for (int j = i; j < 4; ++j)
            red[SYM(i,j)] = hr[i][0]*hr[j][0] + hr[i][1]*hr[j][1];
    #pragma unroll
    for (int j = 0; j < 4; ++j) {
        red[10+j] = hr[j][0]*al0 + hr[j][1]*al1;
        red[14+j] = hr[j][0]*ar0 + hr[j][1]*ar1;
    }
    #pragma unroll
    for (int m = 1; m < 64; m <<= 1)
        #pragma unroll
        for (int r = 0; r < 18; ++r)
            red[r] += __shfl_xor(red[r], m, 64);

    const int miss = missing[b];
    bool pres[4];
    #pragma unroll
    for (int mm = 0; mm < 4; ++mm) pres[mm] = (miss != mm + 1);

    float attn[4][4];
    #pragma unroll
    for (int i = 0; i < 4; ++i) {
        float av[4]; float mx = -3.4e38f;
        #pragma unroll
        for (int j = 0; j < 4; ++j) {
            const bool mk = (i == j) || (pres[i] && pres[j]);
            const float l = (i <= j) ? red[SYM(i,j)] : red[SYM(j,i)];
            float v = (red[14+i] + red[10+j]) * sigmoidf_(l);
            v = (v >= 0.0f) ? v : 0.2f * v;
            av[j] = mk ? v : -1e30f;
            mx = fmaxf(mx, av[j]);
        }
        float den = 0.0f;
        #pragma unroll
        for (int j = 0; j < 4; ++j) { av[j] = __expf(av[j] - mx); den += av[j]; }
        const float inv = 1.0f / den;
        #pragma unroll
        for (int j = 0; j < 4; ++j) attn[i][j] = av[j] * inv;
    }

    const float b0 = bias[cb], b1 = bias[cb+64];
    #pragma unroll
    for (int i = 0; i < 4; ++i) {
        float o0 = b0, o1 = b1;
        #pragma unroll
        for (int j = 0; j < 4; ++j) { o0 += attn[i][j]*hr[j][0]; o1 += attn[i][j]*hr[j][1]; }
        bo[i*512]      = (_Float16)gelu_(o0);
        bo[i*512 + 64] = (_Float16)gelu_(o1);
    }
}

// ------- GAT2 attention + pool + LayerNorm (r20 verbatim) --------------------
__global__ __launch_bounds__(256)
void gat2_attn_kernel(const float* __restrict__ h2,
                      const int* __restrict__ missing,
                      const float* __restrict__ attl, const float* __restrict__ attr,
                      const float* __restrict__ bias,
                      const float* __restrict__ lng, const float* __restrict__ lnb,
                      float* __restrict__ normed)
{
    const int gtid = blockIdx.x * 256 + threadIdx.x;
    const int b = gtid >> 6;
    const int lane = threadIdx.x & 63;
    const float4* hp = (const float4*)(h2 + (size_t)b * 1024);

    float4 hr[4];
    #pragma unroll
    for (int j = 0; j < 4; ++j) hr[j] = hp[j*64 + lane];
    const float4 al = ((const float4*)attl)[lane];
    const float4 ar = ((const float4*)attr)[lane];

    float red[18];
    #pragma unroll
    for (int i = 0; i < 4; ++i)
        #pragma unroll
        for (int j = i; j < 4; ++j)
            red[SYM(i,j)] = hr[i].x*hr[j].x + hr[i].y*hr[j].y + hr[i].z*hr[j].z + hr[i].w*hr[j].w;
    #pragma unroll
    for (int j = 0; j < 4; ++j) {
        red[10+j] = hr[j].x*al.x + hr[j].y*al.y + hr[j].z*al.z + hr[j].w*al.w;
        red[14+j] = hr[j].x*ar.x + hr[j].y*ar.y + hr[j].z*ar.z + hr[j].w*ar.w;
    }
    #pragma unroll
    for (int m = 1; m < 64; m <<= 1)
        #pragma unroll
        for (int r = 0; r < 18; ++r)
            red[r] += __shfl_xor(red[r], m, 64);

    const int miss = missing[b];
    bool pres[4];
    #pragma unroll
    for (int mm = 0; mm < 4; ++mm) pres[mm] = (miss != mm + 1);

    float wsum[4] = {0.f, 0.f, 0.f, 0.f};
    #pragma unroll
    for (int i = 0; i < 4; ++i) {
        float av[4]; float mx = -3.4e38f;
        #pragma unroll
        for (int j = 0; j < 4; ++j) {
            const bool mk = (i == j) || (pres[i] && pres[j]);
            const float l = (i <= j) ? red[SYM(i,j)] : red[SYM(j,i)];
            float v = (red[14+i] + red[10+j]) * sigmoidf_(l);
            v = (v >= 0.0f) ? v : 0.2f * v;
            av[j] = mk ? v : -1e30f;
            mx = fmaxf(mx, av[j]);
        }
        float den = 0.0f;
        #pragma unroll
        for (int j = 0; j < 4; ++j) { av[j] = __expf(av[j] - mx); den += av[j]; }
        const float inv = 0.25f / den;
        #pragma unroll
        for (int j = 0; j < 4; ++j) wsum[j] += av[j] * inv;
    }

    const float4 bv = ((const float4*)bias)[lane];
    float pooled[4] = {bv.x, bv.y, bv.z, bv.w};
    #pragma unroll
    for (int j = 0; j < 4; ++j) {
        pooled[0] += wsum[j] * hr[j].x;
        pooled[1] += wsum[j] * hr[j].y;
        pooled[2] += wsum[j] * hr[j].z;
        pooled[3] += wsum[j] * hr[j].w;
    }

    float s1 = pooled[0] + pooled[1] + pooled[2] + pooled[3];
    float s2 = pooled[0]*pooled[0] + pooled[1]*pooled[1] + pooled[2]*pooled[2] + pooled[3]*pooled[3];
    #pragma unroll
    for (int m = 1; m < 64; m <<= 1) {
        s1 += __shfl_xor(s1, m, 64);
        s2 += __shfl_xor(s2, m, 64);
    }
    const float mu   = s1 * (1.0f / 256.0f);
    const float var  = s2 * (1.0f / 256.0f) - mu * mu;
    const float rstd = rsqrtf(var + 1e-5f);
    const float4 g  = ((const float4*)lng)[lane];
    const float4 bb = ((const float4*)lnb)[lane];
    float4 o;
    o.x = (pooled[0] - mu) * rstd * g.x + bb.x;
    o.y = (pooled[1] - mu) * rstd * g.y + bb.y;
    o.z = (pooled[2] - mu) * rstd * g.z + bb.z;
    o.w = (pooled[3] - mu) * rstd * g.w + bb.w;
    ((float4*)normed)[(size_t)b * 64 + lane] = o;
}

// ---------------- head2 (round-4 verbatim) ----------------------------------
__global__ __launch_bounds__(256)
void head2_kernel(const float* __restrict__ hid, const float* __restrict__ W2,
                  const float* __restrict__ b2, float* __restrict__ out)
{
    const int t = blockIdx.x * 256 + threadIdx.x;
    const int b = t >> 3, o = t & 7;
    const float4* hp = (const float4*)(hid + (size_t)b * 256);
    const float4* wp = (const float4*)(W2 + o * 256);
    float acc = b2[o];
    #pragma unroll 8
    for (int c = 0; c < 64; ++c) {
        const float4 hv = hp[c], wv = wp[c];
        acc += hv.x*wv.x + hv.y*wv.y + hv.z*wv.z + hv.w*wv.w;
    }
    out[t] = acc;
}

// ---------------- launch ----------------------------------------------------
extern "C" void kernel_launch(void* const* d_in, const int* in_sizes, int n_in,
                              void* d_out, int out_size, void* d_ws, size_t ws_size,
                              hipStream_t stream)
{
    (void)in_sizes; (void)n_in; (void)out_size; (void)ws_size;
    const int*   miss  = (const int*)d_in[4];
    const float* g1_al = (const float*)d_in[14];
    const float* g1_ar = (const float*)d_in[15];
    const float* g1_b  = (const float*)d_in[16];
    const float* g2_al = (const float*)d_in[18];
    const float* g2_ar = (const float*)d_in[19];
    const float* g2_b  = (const float*)d_in[20];
    const float* ln_g  = (const float*)d_in[21];
    const float* ln_b  = (const float*)d_in[22];
    const float* h_W2  = (const float*)d_in[25];
    const float* h_b2  = (const float*)d_in[26];
    float* out = (float*)d_out;

    // workspace (MiB offsets; peak 192 MiB, r20 layout):
    char* base = (char*)d_ws;
    _Float16* feats  = (_Float16*)base;
    float*    h1raw  = (float*)   (base + (64ll  << 20));
    _Float16* h1x    = (_Float16*)base;
    float*    h2     = (float*)   (base + (64ll  << 20));
    float*    normed = (float*)   (base + (128ll << 20));
    float*    hid    = (float*)   (base + (144ll << 20));

    const dim3 blkG(512);
    const dim3 blk(256);

    P4 Xs  = {{d_in[0], d_in[1], d_in[2], d_in[3]}};
    P4 Wms = {{d_in[5], d_in[7], d_in[9], d_in[11]}};
    P4 bms = {{d_in[6], d_in[8], d_in[10], d_in[12]}};
    P4 F4  = {{feats, feats, feats, feats}};
    P4 G1W = {{d_in[13], d_in[13], d_in[13], d_in[13]}};
    P4 H1X = {{h1x, h1x, h1x, h1x}};
    P4 G2W = {{d_in[17], d_in[17], d_in[17], d_in[17]}};
    P4 N4  = {{normed, normed, normed, normed}};
    P4 HW1 = {{d_in[23], d_in[23], d_in[23], d_in[23]}};
    P4 HB1 = {{d_in[24], d_in[24], d_in[24], d_in[24]}};
    P4 NUL = {{nullptr, nullptr, nullptr, nullptr}};

    // 1) projections (z-batched, XCD-swizzled: X > L3): feats fp16
    gemm_h8<0, true, true, true, true><<<dim3(2, 128, 4), blkG, 0, stream>>>(
        Xs, Wms, bms, feats, /*K=*/1024, /*lda=*/1024, /*ldc=*/1024, /*zofs=*/256);

    // 2) gat1 linear (no swizzle: feats is L3-fit): h1raw fp32
    gemm_h8<0, false, false, false, false><<<dim3(4, 512, 1), blkG, 0, stream>>>(
        F4, G1W, NUL, h1raw, 256, 256, 512, 0);

    // 3) gat1 attention + bias + gelu: h1raw fp32 -> h1x fp16
    gat1_attn_kernel<<<dim3(16384), blk, 0, stream>>>(
        h1raw, h1x, miss, g1_al, g1_ar, g1_b);

    // 4) gat2 linear (no swizzle): h2 fp32 = h1x(fp16) @ g2_W^T
    gemm_h8<0, false, false, false, false><<<dim3(2, 512, 1), blkG, 0, stream>>>(
        H1X, G2W, NUL, h2, 512, 512, 256, 0);

    // 5) gat2 attention + pool + layernorm -> normed fp32
    gat2_attn_kernel<<<dim3(4096), blk, 0, stream>>>(
        h2, miss, g2_al, g2_ar, g2_b, ln_g, ln_b, normed);

    // 6) head1: hid fp32 = relu(normed @ h_W1^T + h_b1)
    gemm_h8<1, true, false, true, false><<<dim3(2, 128, 1), blkG, 0, stream>>>(
        N4, HW1, HB1, hid, 256, 256, 256, 0);

    // 7) head2: out[16384,8]
    head2_kernel<<<dim3(512), blk, 0, stream>>>(hid, h_W2, h_b2, out);
}

// Round 22
// 341.115 us; speedup vs baseline: 1.3368x; 1.0061x over previous
//
#include <hip/hip_runtime.h>

// B=16384, FEAT=1024, FD=256, M=4 nodes, H1=4x128 (concat->512), H2=1x256, OUT=8.
// Round 22: r21 base (best, 343us) + ONE change: XCD swizzle extended to
// gat1-lin and gat2-lin (panel-sharing x-blocks co-located on one XCD's L2;
// L3-hit latency -> L2-hit latency on latency-bound loops). Pure blockIdx
// remap, grids divisible by 8 -> bijective -> bit-identical math.

typedef __attribute__((ext_vector_type(8))) _Float16 f16x8;
typedef __attribute__((ext_vector_type(4))) float f32x4;

struct P4 { const void* p[4]; };

#define SYM(i,j) ((i)*(7-(i))/2 + (j))

__device__ __forceinline__ float sigmoidf_(float x) { return 1.0f / (1.0f + __expf(-x)); }
__device__ __forceinline__ float gelu_(float x) {
    return 0.5f * x * (1.0f + erff(x * 0.70710678118654752440f));
}

// ---- MFMA NT GEMM, 512 threads = 8 waves (2 row x 4 col), BM=BN=128, BK=32 --
// A fp32 (cvt at ds_write) or fp16 (direct); W fp32 (cvt at ds_write);
// C fp32 (scattered) or fp16 (LDS-transpose epilogue). r13/r18 schedule.
// SWZ: XCD-aware chunked remap of (bx,by).
template<int ACT, bool A_F32, bool OUT_F16, bool HAS_BIAS, bool SWZ>
__global__ __launch_bounds__(512)
void gemm_h8(P4 A4, P4 W4, P4 b4, void* __restrict__ Cv,
             int K, int lda, int ldc, int zofs)
{
    __shared__ __align__(16) unsigned char smem[32768];
    _Float16 (*As)[128][32] = (_Float16(*)[128][32])smem;            // [2][128][32]
    _Float16 (*Bs)[128][32] = (_Float16(*)[128][32])(smem + 16384);  // [2][128][32]
    _Float16 (*outT)[128]   = (_Float16(*)[128])smem;                // [128][128] alias

    const int z = blockIdx.z;
    const float* __restrict__ bias = (const float*)b4.p[z];
    const float* __restrict__ Bw   = (const float*)W4.p[z];

    int bx = blockIdx.x, by = blockIdx.y;
    if constexpr (SWZ) {
        const int nxy  = gridDim.x * gridDim.y;      // divisible by 8 (host-checked)
        const int flat = by * gridDim.x + bx;        // HW dispatch order (x fastest)
        const int chunk = nxy >> 3;
        const int swz = (flat & 7) * chunk + (flat >> 3);
        bx = swz % gridDim.x;
        by = swz / gridDim.x;
    }

    const int t    = threadIdx.x;          // 0..511
    const int lane = t & 63;
    const int w    = t >> 6;               // 0..7
    const int wr   = (w >> 2) << 6;        // 0 / 64
    const int wc   = (w & 3) << 5;         // 0/32/64/96
    const long rowA = (long)by * 128;
    const long colB = (long)bx * 128;

    // B staging (fp32): slot f = t + i*512 -> row f>>3, col (f&7)*4
    const float* Bpt[2];
    int brr[2], bcc[2];
    #pragma unroll
    for (int i = 0; i < 2; ++i) {
        const int f = t + i * 512;
        brr[i] = f >> 3;
        bcc[i] = (f & 7) << 2;
        Bpt[i] = Bw + (colB + brr[i]) * (long)K + bcc[i];
    }
    // A staging
    const float* Apt32[2]; int arr[2], acc_[2];
    const _Float16* Apt16 = nullptr; int a16r = 0, a16c = 0;
    if constexpr (A_F32) {
        const float* A = (const float*)A4.p[z];
        #pragma unroll
        for (int i = 0; i < 2; ++i) {
            const int f = t + i * 512;
            arr[i] = f >> 3;
            acc_[i] = (f & 7) << 2;
            Apt32[i] = A + (rowA + arr[i]) * (long)lda + acc_[i];
        }
    } else {
        const _Float16* A = (const _Float16*)A4.p[z];
        a16r = t >> 2;                 // 0..127
        a16c = (t & 3) << 3;           // 0,8,16,24 (halves)
        Apt16 = A + (rowA + a16r) * (long)lda + a16c;
    }

    f32x4 acc[4][2] = {};
    const int NK = K >> 5;

    float4 aP32[2], aN32[2], bP[2], bN[2];
    uint4  aP16 = {}, aN16 = {};

    // prologue: tile 0 -> regs -> buf0
    if constexpr (A_F32) {
        #pragma unroll
        for (int i = 0; i < 2; ++i) aP32[i] = *(const float4*)(Apt32[i]);
    } else {
        aP16 = *(const uint4*)(Apt16);
    }
    #pragma unroll
    for (int i = 0; i < 2; ++i) bP[i] = *(const float4*)(Bpt[i]);

    if constexpr (A_F32) {
        #pragma unroll
        for (int i = 0; i < 2; ++i) {
            union { _Float16 h[4]; uint2 u; } pa;
            pa.h[0] = (_Float16)aP32[i].x; pa.h[1] = (_Float16)aP32[i].y;
            pa.h[2] = (_Float16)aP32[i].z; pa.h[3] = (_Float16)aP32[i].w;
            *(uint2*)&As[0][arr[i]][acc_[i]] = pa.u;
        }
    } else {
        *(uint4*)&As[0][a16r][a16c] = aP16;
    }
    #pragma unroll
    for (int i = 0; i < 2; ++i) {
        union { _Float16 h[4]; uint2 u; } pb;
        pb.h[0] = (_Float16)bP[i].x; pb.h[1] = (_Float16)bP[i].y;
        pb.h[2] = (_Float16)bP[i].z; pb.h[3] = (_Float16)bP[i].w;
        *(uint2*)&Bs[0][brr[i]][bcc[i]] = pb.u;
    }
    // tile 1 -> regs
    if (NK > 1) {
        if constexpr (A_F32) {
            #pragma unroll
            for (int i = 0; i < 2; ++i) aP32[i] = *(const float4*)(Apt32[i] + 32);
        } else {
            aP16 = *(const uint4*)(Apt16 + 32);
        }
        #pragma unroll
        for (int i = 0; i < 2; ++i) bP[i] = *(const float4*)(Bpt[i] + 32);
    }
    __syncthreads();

    const int fr = lane & 15;
    const int fq = lane >> 4;
    const int fg = fq << 3;

    for (int kk = 0; kk < NK; ++kk) {
        const int cur = kk & 1, nxt = cur ^ 1;

        // 1) ds_write tile kk+1 (regs loaded a full iteration ago)
        if (kk + 1 < NK) {
            if constexpr (A_F32) {
                #pragma unroll
                for (int i = 0; i < 2; ++i) {
                    union { _Float16 h[4]; uint2 u; } pa;
                    pa.h[0] = (_Float16)aP32[i].x; pa.h[1] = (_Float16)aP32[i].y;
                    pa.h[2] = (_Float16)aP32[i].z; pa.h[3] = (_Float16)aP32[i].w;
                    *(uint2*)&As[nxt][arr[i]][acc_[i]] = pa.u;
                }
            } else {
                *(uint4*)&As[nxt][a16r][a16c] = aP16;
            }
            #pragma unroll
            for (int i = 0; i < 2; ++i) {
                union { _Float16 h[4]; uint2 u; } pb;
                pb.h[0] = (_Float16)bP[i].x; pb.h[1] = (_Float16)bP[i].y;
                pb.h[2] = (_Float16)bP[i].z; pb.h[3] = (_Float16)bP[i].w;
                *(uint2*)&Bs[nxt][brr[i]][bcc[i]] = pb.u;
            }
        }

        // 2) issue loads for tile kk+2
        if (kk + 2 < NK) {
            const int ko = (kk + 2) << 5;
            if constexpr (A_F32) {
                #pragma unroll
                for (int i = 0; i < 2; ++i) aN32[i] = *(const float4*)(Apt32[i] + ko);
            } else {
                aN16 = *(const uint4*)(Apt16 + ko);
            }
            #pragma unroll
            for (int i = 0; i < 2; ++i) bN[i] = *(const float4*)(Bpt[i] + ko);
        }

        // 3) fragments + MFMA on buf[cur]
        f16x8 af[4], bf[2];
        #pragma unroll
        for (int m = 0; m < 4; ++m) af[m] = *(const f16x8*)&As[cur][wr + m*16 + fr][fg];
        #pragma unroll
        for (int n = 0; n < 2; ++n) bf[n] = *(const f16x8*)&Bs[cur][wc + n*16 + fr][fg];
        #pragma unroll
        for (int m = 0; m < 4; ++m)
            #pragma unroll
            for (int n = 0; n < 2; ++n)
                acc[m][n] = __builtin_amdgcn_mfma_f32_16x16x32_f16(af[m], bf[n], acc[m][n], 0, 0, 0);

        // 4) barrier; 5) roll prefetch regs
        __syncthreads();
        if (kk + 2 < NK) {
            if constexpr (A_F32) {
                #pragma unroll
                for (int i = 0; i < 2; ++i) aP32[i] = aN32[i];
            } else {
                aP16 = aN16;
            }
            #pragma unroll
            for (int i = 0; i < 2; ++i) bP[i] = bN[i];
        }
    }

    if constexpr (OUT_F16) {
        _Float16* Cz = (_Float16*)Cv + (long)z * zofs;
        __syncthreads();   // all frag reads done; outT aliases staging
        float bn[2];
        #pragma unroll
        for (int n = 0; n < 2; ++n)
            bn[n] = HAS_BIAS ? bias[colB + wc + n*16 + fr] : 0.0f;
        #pragma unroll
        for (int m = 0; m < 4; ++m)
            #pragma unroll
            for (int n = 0; n < 2; ++n)
                #pragma unroll
                for (int j = 0; j < 4; ++j) {
                    float x = acc[m][n][j] + bn[n];
                    if (ACT == 1) x = fmaxf(x, 0.0f);
                    outT[wr + m*16 + fq*4 + j][wc + n*16 + fr] = (_Float16)x;
                }
        __syncthreads();
        #pragma unroll
        for (int i = 0; i < 4; ++i) {
            const int s = t + i * 512;
            const int r = s >> 4, c = (s & 15) << 3;
            *(uint4*)(Cz + (rowA + r) * (long)ldc + colB + c) = *(const uint4*)&outT[r][c];
        }
    } else {
        float* Cz = (float*)Cv + (long)z * zofs;
        #pragma unroll
        for (int n = 0; n < 2; ++n) {
            const long col = colB + wc + n*16 + fr;
            const float bn = HAS_BIAS ? bias[col] : 0.0f;
            #pragma unroll
            for (int m = 0; m < 4; ++m) {
                const long row0 = rowA + wr + m*16 + fq*4;
                #pragma unroll
                for (int j = 0; j < 4; ++j) {
                    float x = acc[m][n][j] + bn;
                    if (ACT == 1) x = fmaxf(x, 0.0f);
                    Cz[(row0 + j) * (long)ldc + col] = x;
                }
            }
        }
    }
}

// -- GAT1 attention (r20 verbatim): reads fp32 h1raw, writes fp16 h1x ---------
__global__ __launch_bounds__(256)
void gat1_attn_kernel(const float* __restrict__ h1raw,
                      _Float16* __restrict__ h1x,
                      const int* __restrict__ missing,
                      const float* __restrict__ attl, const float* __restrict__ attr,
                      const float* __restrict__ bias)
{
    const int gtid = blockIdx.x * 256 + threadIdx.x;
    const int wid  = gtid >> 6;
    const int lane = threadIdx.x & 63;
    const int b = wid >> 2;
    const int h = wid & 3;
    const int cb = h * 128 + lane;
    const float* bi = h1raw + (size_t)b * 2048 + cb;
    _Float16*   bo = h1x   + (size_t)b * 2048 + cb;

    float hr[4][2];
    #pragma unroll
    for (int j = 0; j < 4; ++j) { hr[j][0] = bi[j*512]; hr[j][1] = bi[j*512 + 64]; }
    const float al0 = attl[cb], al1 = attl[cb+64];
    const float ar0 = attr[cb], ar1 = attr[cb+64];

    float red[18];
    #pragma unroll
    for (int i = 0; i < 4; ++i)
        #pragma unroll
        for (int j = i; j < 4; ++j)
            red[SYM(i,j)] = hr[i][0]*hr[j][0] + hr[i][1]*hr[j][1];
    #pragma unroll
    for (int j = 0; j < 4; ++j) {
        red[10+j] = hr[j][0]*al0 + hr[j][1]*al1;
        red[14+j] = hr[j][0]*ar0 + hr[j][1]*ar1;
    }
    #pragma unroll
    for (int m = 1; m < 64; m <<= 1)
        #pragma unroll
        for (int r = 0; r < 18; ++r)
            red[r] += __shfl_xor(red[r], m, 64);

    const int miss = missing[b];
    bool pres[4];
    #pragma unroll
    for (int mm = 0; mm < 4; ++mm) pres[mm] = (miss != mm + 1);

    float attn[4][4];
    #pragma unroll
    for (int i = 0; i < 4; ++i) {
        float av[4]; float mx = -3.4e38f;
        #pragma unroll
        for (int j = 0; j < 4; ++j) {
            const bool mk = (i == j) || (pres[i] && pres[j]);
            const float l = (i <= j) ? red[SYM(i,j)] : red[SYM(j,i)];
            float v = (red[14+i] + red[10+j]) * sigmoidf_(l);
            v = (v >= 0.0f) ? v : 0.2f * v;
            av[j] = mk ? v : -1e30f;
            mx = fmaxf(mx, av[j]);
        }
        float den = 0.0f;
        #pragma unroll
        for (int j = 0; j < 4; ++j) { av[j] = __expf(av[j] - mx); den += av[j]; }
        const float inv = 1.0f / den;
        #pragma unroll
        for (int j = 0; j < 4; ++j) attn[i][j] = av[j] * inv;
    }

    const float b0 = bias[cb], b1 = bias[cb+64];
    #pragma unroll
    for (int i = 0; i < 4; ++i) {
        float o0 = b0, o1 = b1;
        #pragma unroll
        for (int j = 0; j < 4; ++j) { o0 += attn[i][j]*hr[j][0]; o1 += attn[i][j]*hr[j][1]; }
        bo[i*512]      = (_Float16)gelu_(o0);
        bo[i*512 + 64] = (_Float16)gelu_(o1);
    }
}

// ------- GAT2 attention + pool + LayerNorm (r20 verbatim) --------------------
__global__ __launch_bounds__(256)
void gat2_attn_kernel(const float* __restrict__ h2,
                      const int* __restrict__ missing,
                      const float* __restrict__ attl, const float* __restrict__ attr,
                      const float* __restrict__ bias,
                      const float* __restrict__ lng, const float* __restrict__ lnb,
                      float* __restrict__ normed)
{
    const int gtid = blockIdx.x * 256 + threadIdx.x;
    const int b = gtid >> 6;
    const int lane = threadIdx.x & 63;
    const float4* hp = (const float4*)(h2 + (size_t)b * 1024);

    float4 hr[4];
    #pragma unroll
    for (int j = 0; j < 4; ++j) hr[j] = hp[j*64 + lane];
    const float4 al = ((const float4*)attl)[lane];
    const float4 ar = ((const float4*)attr)[lane];

    float red[18];
    #pragma unroll
    for (int i = 0; i < 4; ++i)
        #pragma unroll
        for (int j = i; j < 4; ++j)
            red[SYM(i,j)] = hr[i].x*hr[j].x + hr[i].y*hr[j].y + hr[i].z*hr[j].z + hr[i].w*hr[j].w;
    #pragma unroll
    for (int j = 0; j < 4; ++j) {
        red[10+j] = hr[j].x*al.x + hr[j].y*al.y + hr[j].z*al.z + hr[j].w*al.w;
        red[14+j] = hr[j].x*ar.x + hr[j].y*ar.y + hr[j].z*ar.z + hr[j].w*ar.w;
    }
    #pragma unroll
    for (int m = 1; m < 64; m <<= 1)
        #pragma unroll
        for (int r = 0; r < 18; ++r)
            red[r] += __shfl_xor(red[r], m, 64);

    const int miss = missing[b];
    bool pres[4];
    #pragma unroll
    for (int mm = 0; mm < 4; ++mm) pres[mm] = (miss != mm + 1);

    float wsum[4] = {0.f, 0.f, 0.f, 0.f};
    #pragma unroll
    for (int i = 0; i < 4; ++i) {
        float av[4]; float mx = -3.4e38f;
        #pragma unroll
        for (int j = 0; j < 4; ++j) {
            const bool mk = (i == j) || (pres[i] && pres[j]);
            const float l = (i <= j) ? red[SYM(i,j)] : red[SYM(j,i)];
            float v = (red[14+i] + red[10+j]) * sigmoidf_(l);
            v = (v >= 0.0f) ? v : 0.2f * v;
            av[j] = mk ? v : -1e30f;
            mx = fmaxf(mx, av[j]);
        }
        float den = 0.0f;
        #pragma unroll
        for (int j = 0; j < 4; ++j) { av[j] = __expf(av[j] - mx); den += av[j]; }
        const float inv = 0.25f / den;
        #pragma unroll
        for (int j = 0; j < 4; ++j) wsum[j] += av[j] * inv;
    }

    const float4 bv = ((const float4*)bias)[lane];
    float pooled[4] = {bv.x, bv.y, bv.z, bv.w};
    #pragma unroll
    for (int j = 0; j < 4; ++j) {
        pooled[0] += wsum[j] * hr[j].x;
        pooled[1] += wsum[j] * hr[j].y;
        pooled[2] += wsum[j] * hr[j].z;
        pooled[3] += wsum[j] * hr[j].w;
    }

    float s1 = pooled[0] + pooled[1] + pooled[2] + pooled[3];
    float s2 = pooled[0]*pooled[0] + pooled[1]*pooled[1] + pooled[2]*pooled[2] + pooled[3]*pooled[3];
    #pragma unroll
    for (int m = 1; m < 64; m <<= 1) {
        s1 += __shfl_xor(s1, m, 64);
        s2 += __shfl_xor(s2, m, 64);
    }
    const float mu   = s1 * (1.0f / 256.0f);
    const float var  = s2 * (1.0f / 256.0f) - mu * mu;
    const float rstd = rsqrtf(var + 1e-5f);
    const float4 g  = ((const float4*)lng)[lane];
    const float4 bb = ((const float4*)lnb)[lane];
    float4 o;
    o.x = (pooled[0] - mu) * rstd * g.x + bb.x;
    o.y = (pooled[1] - mu) * rstd * g.y + bb.y;
    o.z = (pooled[2] - mu) * rstd * g.z + bb.z;
    o.w = (pooled[3] - mu) * rstd * g.w + bb.w;
    ((float4*)normed)[(size_t)b * 64 + lane] = o;
}

// ---------------- head2 (round-4 verbatim) ----------------------------------
__global__ __launch_bounds__(256)
void head2_kernel(const float* __restrict__ hid, const float* __restrict__ W2,
                  const float* __restrict__ b2, float* __restrict__ out)
{
    const int t = blockIdx.x * 256 + threadIdx.x;
    const int b = t >> 3, o = t & 7;
    const float4* hp = (const float4*)(hid + (size_t)b * 256);
    const float4* wp = (const float4*)(W2 + o * 256);
    float acc = b2[o];
    #pragma unroll 8
    for (int c = 0; c < 64; ++c) {
        const float4 hv = hp[c], wv = wp[c];
        acc += hv.x*wv.x + hv.y*wv.y + hv.z*wv.z + hv.w*wv.w;
    }
    out[t] = acc;
}

// ---------------- launch ----------------------------------------------------
extern "C" void kernel_launch(void* const* d_in, const int* in_sizes, int n_in,
                              void* d_out, int out_size, void* d_ws, size_t ws_size,
                              hipStream_t stream)
{
    (void)in_sizes; (void)n_in; (void)out_size; (void)ws_size;
    const int*   miss  = (const int*)d_in[4];
    const float* g1_al = (const float*)d_in[14];
    const float* g1_ar = (const float*)d_in[15];
    const float* g1_b  = (const float*)d_in[16];
    const float* g2_al = (const float*)d_in[18];
    const float* g2_ar = (const float*)d_in[19];
    const float* g2_b  = (const float*)d_in[20];
    const float* ln_g  = (const float*)d_in[21];
    const float* ln_b  = (const float*)d_in[22];
    const float* h_W2  = (const float*)d_in[25];
    const float* h_b2  = (const float*)d_in[26];
    float* out = (float*)d_out;

    // workspace (MiB offsets; peak 192 MiB, r20 layout):
    char* base = (char*)d_ws;
    _Float16* feats  = (_Float16*)base;
    float*    h1raw  = (float*)   (base + (64ll  << 20));
    _Float16* h1x    = (_Float16*)base;
    float*    h2     = (float*)   (base + (64ll  << 20));
    float*    normed = (float*)   (base + (128ll << 20));
    float*    hid    = (float*)   (base + (144ll << 20));

    const dim3 blkG(512);
    const dim3 blk(256);

    P4 Xs  = {{d_in[0], d_in[1], d_in[2], d_in[3]}};
    P4 Wms = {{d_in[5], d_in[7], d_in[9], d_in[11]}};
    P4 bms = {{d_in[6], d_in[8], d_in[10], d_in[12]}};
    P4 F4  = {{feats, feats, feats, feats}};
    P4 G1W = {{d_in[13], d_in[13], d_in[13], d_in[13]}};
    P4 H1X = {{h1x, h1x, h1x, h1x}};
    P4 G2W = {{d_in[17], d_in[17], d_in[17], d_in[17]}};
    P4 N4  = {{normed, normed, normed, normed}};
    P4 HW1 = {{d_in[23], d_in[23], d_in[23], d_in[23]}};
    P4 HB1 = {{d_in[24], d_in[24], d_in[24], d_in[24]}};
    P4 NUL = {{nullptr, nullptr, nullptr, nullptr}};

    // 1) projections (z-batched, XCD-swizzled): feats fp16
    gemm_h8<0, true, true, true, true><<<dim3(2, 128, 4), blkG, 0, stream>>>(
        Xs, Wms, bms, feats, /*K=*/1024, /*lda=*/1024, /*ldc=*/1024, /*zofs=*/256);

    // 2) gat1 linear (XCD-swizzled): h1raw fp32 = feats(fp16) @ g1_W^T
    gemm_h8<0, false, false, false, true><<<dim3(4, 512, 1), blkG, 0, stream>>>(
        F4, G1W, NUL, h1raw, 256, 256, 512, 0);

    // 3) gat1 attention + bias + gelu: h1raw fp32 -> h1x fp16
    gat1_attn_kernel<<<dim3(16384), blk, 0, stream>>>(
        h1raw, h1x, miss, g1_al, g1_ar, g1_b);

    // 4) gat2 linear (XCD-swizzled): h2 fp32 = h1x(fp16) @ g2_W^T
    gemm_h8<0, false, false, false, true><<<dim3(2, 512, 1), blkG, 0, stream>>>(
        H1X, G2W, NUL, h2, 512, 512, 256, 0);

    // 5) gat2 attention + pool + layernorm -> normed fp32
    gat2_attn_kernel<<<dim3(4096), blk, 0, stream>>>(
        h2, miss, g2_al, g2_ar, g2_b, ln_g, ln_b, normed);

    // 6) head1: hid fp32 = relu(normed @ h_W1^T + h_b1)
    gemm_h8<1, true, false, true, false><<<dim3(2, 128, 1), blkG, 0, stream>>>(
        N4, HW1, HB1, hid, 256, 256, 256, 0);

    // 7) head2: out[16384,8]
    head2_kernel<<<dim3(512), blk, 0, stream>>>(hid, h_W2, h_b2, out);
}

// Round 23
// 334.045 us; speedup vs baseline: 1.3651x; 1.0212x over previous
//
#include <hip/hip_runtime.h>

// B=16384, FEAT=1024, FD=256, M=4 nodes, H1=4x128 (concat->512), H2=1x256, OUT=8.
// Round 23: r22 base (best, 341us) + ONE deliberate numeric change: h1 stored
// fp16 (gat1-lin uses the validated OUT_F16 transpose epilogue; gat1_attn
// reads fp16). Saves ~134MB of h1 traffic. Predicted absmax 0.01-0.02
// (logit RMS err ~0.016 -> output ~0.01), threshold 0.038. Revert if fail.

typedef __attribute__((ext_vector_type(8))) _Float16 f16x8;
typedef __attribute__((ext_vector_type(4))) float f32x4;

struct P4 { const void* p[4]; };

#define SYM(i,j) ((i)*(7-(i))/2 + (j))

__device__ __forceinline__ float sigmoidf_(float x) { return 1.0f / (1.0f + __expf(-x)); }
__device__ __forceinline__ float gelu_(float x) {
    return 0.5f * x * (1.0f + erff(x * 0.70710678118654752440f));
}

// ---- MFMA NT GEMM, 512 threads = 8 waves (2 row x 4 col), BM=BN=128, BK=32 --
// (r22 verbatim) A fp32 (cvt at ds_write) or fp16 (direct); W fp32 (cvt);
// C fp32 (scattered) or fp16 (LDS-transpose epilogue). SWZ: XCD chunked remap.
template<int ACT, bool A_F32, bool OUT_F16, bool HAS_BIAS, bool SWZ>
__global__ __launch_bounds__(512)
void gemm_h8(P4 A4, P4 W4, P4 b4, void* __restrict__ Cv,
             int K, int lda, int ldc, int zofs)
{
    __shared__ __align__(16) unsigned char smem[32768];
    _Float16 (*As)[128][32] = (_Float16(*)[128][32])smem;            // [2][128][32]
    _Float16 (*Bs)[128][32] = (_Float16(*)[128][32])(smem + 16384);  // [2][128][32]
    _Float16 (*outT)[128]   = (_Float16(*)[128])smem;                // [128][128] alias

    const int z = blockIdx.z;
    const float* __restrict__ bias = (const float*)b4.p[z];
    const float* __restrict__ Bw   = (const float*)W4.p[z];

    int bx = blockIdx.x, by = blockIdx.y;
    if constexpr (SWZ) {
        const int nxy  = gridDim.x * gridDim.y;
        const int flat = by * gridDim.x + bx;
        const int chunk = nxy >> 3;
        const int swz = (flat & 7) * chunk + (flat >> 3);
        bx = swz % gridDim.x;
        by = swz / gridDim.x;
    }

    const int t    = threadIdx.x;
    const int lane = t & 63;
    const int w    = t >> 6;
    const int wr   = (w >> 2) << 6;
    const int wc   = (w & 3) << 5;
    const long rowA = (long)by * 128;
    const long colB = (long)bx * 128;

    const float* Bpt[2];
    int brr[2], bcc[2];
    #pragma unroll
    for (int i = 0; i < 2; ++i) {
        const int f = t + i * 512;
        brr[i] = f >> 3;
        bcc[i] = (f & 7) << 2;
        Bpt[i] = Bw + (colB + brr[i]) * (long)K + bcc[i];
    }
    const float* Apt32[2]; int arr[2], acc_[2];
    const _Float16* Apt16 = nullptr; int a16r = 0, a16c = 0;
    if constexpr (A_F32) {
        const float* A = (const float*)A4.p[z];
        #pragma unroll
        for (int i = 0; i < 2; ++i) {
            const int f = t + i * 512;
            arr[i] = f >> 3;
            acc_[i] = (f & 7) << 2;
            Apt32[i] = A + (rowA + arr[i]) * (long)lda + acc_[i];
        }
    } else {
        const _Float16* A = (const _Float16*)A4.p[z];
        a16r = t >> 2;
        a16c = (t & 3) << 3;
        Apt16 = A + (rowA + a16r) * (long)lda + a16c;
    }

    f32x4 acc[4][2] = {};
    const int NK = K >> 5;

    float4 aP32[2], aN32[2], bP[2], bN[2];
    uint4  aP16 = {}, aN16 = {};

    if constexpr (A_F32) {
        #pragma unroll
        for (int i = 0; i < 2; ++i) aP32[i] = *(const float4*)(Apt32[i]);
    } else {
        aP16 = *(const uint4*)(Apt16);
    }
    #pragma unroll
    for (int i = 0; i < 2; ++i) bP[i] = *(const float4*)(Bpt[i]);

    if constexpr (A_F32) {
        #pragma unroll
        for (int i = 0; i < 2; ++i) {
            union { _Float16 h[4]; uint2 u; } pa;
            pa.h[0] = (_Float16)aP32[i].x; pa.h[1] = (_Float16)aP32[i].y;
            pa.h[2] = (_Float16)aP32[i].z; pa.h[3] = (_Float16)aP32[i].w;
            *(uint2*)&As[0][arr[i]][acc_[i]] = pa.u;
        }
    } else {
        *(uint4*)&As[0][a16r][a16c] = aP16;
    }
    #pragma unroll
    for (int i = 0; i < 2; ++i) {
        union { _Float16 h[4]; uint2 u; } pb;
        pb.h[0] = (_Float16)bP[i].x; pb.h[1] = (_Float16)bP[i].y;
        pb.h[2] = (_Float16)bP[i].z; pb.h[3] = (_Float16)bP[i].w;
        *(uint2*)&Bs[0][brr[i]][bcc[i]] = pb.u;
    }
    if (NK > 1) {
        if constexpr (A_F32) {
            #pragma unroll
            for (int i = 0; i < 2; ++i) aP32[i] = *(const float4*)(Apt32[i] + 32);
        } else {
            aP16 = *(const uint4*)(Apt16 + 32);
        }
        #pragma unroll
        for (int i = 0; i < 2; ++i) bP[i] = *(const float4*)(Bpt[i] + 32);
    }
    __syncthreads();

    const int fr = lane & 15;
    const int fq = lane >> 4;
    const int fg = fq << 3;

    for (int kk = 0; kk < NK; ++kk) {
        const int cur = kk & 1, nxt = cur ^ 1;

        if (kk + 1 < NK) {
            if constexpr (A_F32) {
                #pragma unroll
                for (int i = 0; i < 2; ++i) {
                    union { _Float16 h[4]; uint2 u; } pa;
                    pa.h[0] = (_Float16)aP32[i].x; pa.h[1] = (_Float16)aP32[i].y;
                    pa.h[2] = (_Float16)aP32[i].z; pa.h[3] = (_Float16)aP32[i].w;
                    *(uint2*)&As[nxt][arr[i]][acc_[i]] = pa.u;
                }
            } else {
                *(uint4*)&As[nxt][a16r][a16c] = aP16;
            }
            #pragma unroll
            for (int i = 0; i < 2; ++i) {
                union { _Float16 h[4]; uint2 u; } pb;
                pb.h[0] = (_Float16)bP[i].x; pb.h[1] = (_Float16)bP[i].y;
                pb.h[2] = (_Float16)bP[i].z; pb.h[3] = (_Float16)bP[i].w;
                *(uint2*)&Bs[nxt][brr[i]][bcc[i]] = pb.u;
            }
        }

        if (kk + 2 < NK) {
            const int ko = (kk + 2) << 5;
            if constexpr (A_F32) {
                #pragma unroll
                for (int i = 0; i < 2; ++i) aN32[i] = *(const float4*)(Apt32[i] + ko);
            } else {
                aN16 = *(const uint4*)(Apt16 + ko);
            }
            #pragma unroll
            for (int i = 0; i < 2; ++i) bN[i] = *(const float4*)(Bpt[i] + ko);
        }

        f16x8 af[4], bf[2];
        #pragma unroll
        for (int m = 0; m < 4; ++m) af[m] = *(const f16x8*)&As[cur][wr + m*16 + fr][fg];
        #pragma unroll
        for (int n = 0; n < 2; ++n) bf[n] = *(const f16x8*)&Bs[cur][wc + n*16 + fr][fg];
        #pragma unroll
        for (int m = 0; m < 4; ++m)
            #pragma unroll
            for (int n = 0; n < 2; ++n)
                acc[m][n] = __builtin_amdgcn_mfma_f32_16x16x32_f16(af[m], bf[n], acc[m][n], 0, 0, 0);

        __syncthreads();
        if (kk + 2 < NK) {
            if constexpr (A_F32) {
                #pragma unroll
                for (int i = 0; i < 2; ++i) aP32[i] = aN32[i];
            } else {
                aP16 = aN16;
            }
            #pragma unroll
            for (int i = 0; i < 2; ++i) bP[i] = bN[i];
        }
    }

    if constexpr (OUT_F16) {
        _Float16* Cz = (_Float16*)Cv + (long)z * zofs;
        __syncthreads();
        float bn[2];
        #pragma unroll
        for (int n = 0; n < 2; ++n)
            bn[n] = HAS_BIAS ? bias[colB + wc + n*16 + fr] : 0.0f;
        #pragma unroll
        for (int m = 0; m < 4; ++m)
            #pragma unroll
            for (int n = 0; n < 2; ++n)
                #pragma unroll
                for (int j = 0; j < 4; ++j) {
                    float x = acc[m][n][j] + bn[n];
                    if (ACT == 1) x = fmaxf(x, 0.0f);
                    outT[wr + m*16 + fq*4 + j][wc + n*16 + fr] = (_Float16)x;
                }
        __syncthreads();
        #pragma unroll
        for (int i = 0; i < 4; ++i) {
            const int s = t + i * 512;
            const int r = s >> 4, c = (s & 15) << 3;
            *(uint4*)(Cz + (rowA + r) * (long)ldc + colB + c) = *(const uint4*)&outT[r][c];
        }
    } else {
        float* Cz = (float*)Cv + (long)z * zofs;
        #pragma unroll
        for (int n = 0; n < 2; ++n) {
            const long col = colB + wc + n*16 + fr;
            const float bn = HAS_BIAS ? bias[col] : 0.0f;
            #pragma unroll
            for (int m = 0; m < 4; ++m) {
                const long row0 = rowA + wr + m*16 + fq*4;
                #pragma unroll
                for (int j = 0; j < 4; ++j) {
                    float x = acc[m][n][j] + bn;
                    if (ACT == 1) x = fmaxf(x, 0.0f);
                    Cz[(row0 + j) * (long)ldc + col] = x;
                }
            }
        }
    }
}

// -- GAT1 attention: reads fp16 h1f, computes fp32, writes fp16 h1x ----------
__global__ __launch_bounds__(256)
void gat1_attn_kernel(const _Float16* __restrict__ h1f,
                      _Float16* __restrict__ h1x,
                      const int* __restrict__ missing,
                      const float* __restrict__ attl, const float* __restrict__ attr,
                      const float* __restrict__ bias)
{
    const int gtid = blockIdx.x * 256 + threadIdx.x;
    const int wid  = gtid >> 6;
    const int lane = threadIdx.x & 63;
    const int b = wid >> 2;
    const int h = wid & 3;
    const int cb = h * 128 + lane;
    const _Float16* bi = h1f + (size_t)b * 2048 + cb;
    _Float16*       bo = h1x + (size_t)b * 2048 + cb;

    float hr[4][2];
    #pragma unroll
    for (int j = 0; j < 4; ++j) {
        hr[j][0] = (float)bi[j*512];
        hr[j][1] = (float)bi[j*512 + 64];
    }
    const float al0 = attl[cb], al1 = attl[cb+64];
    const float ar0 = attr[cb], ar1 = attr[cb+64];

    float red[18];
    #pragma unroll
    for (int i = 0; i < 4; ++i)
        #pragma unroll
        for (int j = i; j < 4; ++j)
            red[SYM(i,j)] = hr[i][0]*hr[j][0] + hr[i][1]*hr[j][1];
    #pragma unroll
    for (int j = 0; j < 4; ++j) {
        red[10+j] = hr[j][0]*al0 + hr[j][1]*al1;
        red[14+j] = hr[j][0]*ar0 + hr[j][1]*ar1;
    }
    #pragma unroll
    for (int m = 1; m < 64; m <<= 1)
        #pragma unroll
        for (int r = 0; r < 18; ++r)
            red[r] += __shfl_xor(red[r], m, 64);

    const int miss = missing[b];
    bool pres[4];
    #pragma unroll
    for (int mm = 0; mm < 4; ++mm) pres[mm] = (miss != mm + 1);

    float attn[4][4];
    #pragma unroll
    for (int i = 0; i < 4; ++i) {
        float av[4]; float mx = -3.4e38f;
        #pragma unroll
        for (int j = 0; j < 4; ++j) {
            const bool mk = (i == j) || (pres[i] && pres[j]);
            const float l = (i <= j) ? red[SYM(i,j)] : red[SYM(j,i)];
            float v = (red[14+i] + red[10+j]) * sigmoidf_(l);
            v = (v >= 0.0f) ? v : 0.2f * v;
            av[j] = mk ? v : -1e30f;
            mx = fmaxf(mx, av[j]);
        }
        float den = 0.0f;
        #pragma unroll
        for (int j = 0; j < 4; ++j) { av[j] = __expf(av[j] - mx); den += av[j]; }
        const float inv = 1.0f / den;
        #pragma unroll
        for (int j = 0; j < 4; ++j) attn[i][j] = av[j] * inv;
    }

    const float b0 = bias[cb], b1 = bias[cb+64];
    #pragma unroll
    for (int i = 0; i < 4; ++i) {
        float o0 = b0, o1 = b1;
        #pragma unroll
        for (int j = 0; j < 4; ++j) { o0 += attn[i][j]*hr[j][0]; o1 += attn[i][j]*hr[j][1]; }
        bo[i*512]      = (_Float16)gelu_(o0);
        bo[i*512 + 64] = (_Float16)gelu_(o1);
    }
}

// ------- GAT2 attention + pool + LayerNorm (r22 verbatim) --------------------
__global__ __launch_bounds__(256)
void gat2_attn_kernel(const float* __restrict__ h2,
                      const int* __restrict__ missing,
                      const float* __restrict__ attl, const float* __restrict__ attr,
                      const float* __restrict__ bias,
                      const float* __restrict__ lng, const float* __restrict__ lnb,
                      float* __restrict__ normed)
{
    const int gtid = blockIdx.x * 256 + threadIdx.x;
    const int b = gtid >> 6;
    const int lane = threadIdx.x & 63;
    const float4* hp = (const float4*)(h2 + (size_t)b * 1024);

    float4 hr[4];
    #pragma unroll
    for (int j = 0; j < 4; ++j) hr[j] = hp[j*64 + lane];
    const float4 al = ((const float4*)attl)[lane];
    const float4 ar = ((const float4*)attr)[lane];

    float red[18];
    #pragma unroll
    for (int i = 0; i < 4; ++i)
        #pragma unroll
        for (int j = i; j < 4; ++j)
            red[SYM(i,j)] = hr[i].x*hr[j].x + hr[i].y*hr[j].y + hr[i].z*hr[j].z + hr[i].w*hr[j].w;
    #pragma unroll
    for (int j = 0; j < 4; ++j) {
        red[10+j] = hr[j].x*al.x + hr[j].y*al.y + hr[j].z*al.z + hr[j].w*al.w;
        red[14+j] = hr[j].x*ar.x + hr[j].y*ar.y + hr[j].z*ar.z + hr[j].w*ar.w;
    }
    #pragma unroll
    for (int m = 1; m < 64; m <<= 1)
        #pragma unroll
        for (int r = 0; r < 18; ++r)
            red[r] += __shfl_xor(red[r], m, 64);

    const int miss = missing[b];
    bool pres[4];
    #pragma unroll
    for (int mm = 0; mm < 4; ++mm) pres[mm] = (miss != mm + 1);

    float wsum[4] = {0.f, 0.f, 0.f, 0.f};
    #pragma unroll
    for (int i = 0; i < 4; ++i) {
        float av[4]; float mx = -3.4e38f;
        #pragma unroll
        for (int j = 0; j < 4; ++j) {
            const bool mk = (i == j) || (pres[i] && pres[j]);
            const float l = (i <= j) ? red[SYM(i,j)] : red[SYM(j,i)];
            float v = (red[14+i] + red[10+j]) * sigmoidf_(l);
            v = (v >= 0.0f) ? v : 0.2f * v;
            av[j] = mk ? v : -1e30f;
            mx = fmaxf(mx, av[j]);
        }
        float den = 0.0f;
        #pragma unroll
        for (int j = 0; j < 4; ++j) { av[j] = __expf(av[j] - mx); den += av[j]; }
        const float inv = 0.25f / den;
        #pragma unroll
        for (int j = 0; j < 4; ++j) wsum[j] += av[j] * inv;
    }

    const float4 bv = ((const float4*)bias)[lane];
    float pooled[4] = {bv.x, bv.y, bv.z, bv.w};
    #pragma unroll
    for (int j = 0; j < 4; ++j) {
        pooled[0] += wsum[j] * hr[j].x;
        pooled[1] += wsum[j] * hr[j].y;
        pooled[2] += wsum[j] * hr[j].z;
        pooled[3] += wsum[j] * hr[j].w;
    }

    float s1 = pooled[0] + pooled[1] + pooled[2] + pooled[3];
    float s2 = pooled[0]*pooled[0] + pooled[1]*pooled[1] + pooled[2]*pooled[2] + pooled[3]*pooled[3];
    #pragma unroll
    for (int m = 1; m < 64; m <<= 1) {
        s1 += __shfl_xor(s1, m, 64);
        s2 += __shfl_xor(s2, m, 64);
    }
    const float mu   = s1 * (1.0f / 256.0f);
    const float var  = s2 * (1.0f / 256.0f) - mu * mu;
    const float rstd = rsqrtf(var + 1e-5f);
    const float4 g  = ((const float4*)lng)[lane];
    const float4 bb = ((const float4*)lnb)[lane];
    float4 o;
    o.x = (pooled[0] - mu) * rstd * g.x + bb.x;
    o.y = (pooled[1] - mu) * rstd * g.y + bb.y;
    o.z = (pooled[2] - mu) * rstd * g.z + bb.z;
    o.w = (pooled[3] - mu) * rstd * g.w + bb.w;
    ((float4*)normed)[(size_t)b * 64 + lane] = o;
}

// ---------------- head2 (round-4 verbatim) ----------------------------------
__global__ __launch_bounds__(256)
void head2_kernel(const float* __restrict__ hid, const float* __restrict__ W2,
                  const float* __restrict__ b2, float* __restrict__ out)
{
    const int t = blockIdx.x * 256 + threadIdx.x;
    const int b = t >> 3, o = t & 7;
    const float4* hp = (const float4*)(hid + (size_t)b * 256);
    const float4* wp = (const float4*)(W2 + o * 256);
    float acc = b2[o];
    #pragma unroll 8
    for (int c = 0; c < 64; ++c) {
        const float4 hv = hp[c], wv = wp[c];
        acc += hv.x*wv.x + hv.y*wv.y + hv.z*wv.z + hv.w*wv.w;
    }
    out[t] = acc;
}

// ---------------- launch ----------------------------------------------------
extern "C" void kernel_launch(void* const* d_in, const int* in_sizes, int n_in,
                              void* d_out, int out_size, void* d_ws, size_t ws_size,
                              hipStream_t stream)
{
    (void)in_sizes; (void)n_in; (void)out_size; (void)ws_size;
    const int*   miss  = (const int*)d_in[4];
    const float* g1_al = (const float*)d_in[14];
    const float* g1_ar = (const float*)d_in[15];
    const float* g1_b  = (const float*)d_in[16];
    const float* g2_al = (const float*)d_in[18];
    const float* g2_ar = (const float*)d_in[19];
    const float* g2_b  = (const float*)d_in[20];
    const float* ln_g  = (const float*)d_in[21];
    const float* ln_b  = (const float*)d_in[22];
    const float* h_W2  = (const float*)d_in[25];
    const float* h_b2  = (const float*)d_in[26];
    float* out = (float*)d_out;

    // workspace (MiB offsets; peak 192 MiB):
    //   feats  fp16 [16384,1024] @   0  (32)  -> dead after gat1-lin
    //   h1f    fp16 [65536,512]  @  64  (64)  -> dead after gat1_attn
    //   h1x    fp16 [65536,512]  @   0  (64)  (overwrites dead feats)
    //   h2     fp32 [65536,256]  @ 128  (64)
    //   normed fp32 [16384,256]  @  64  (16)  (overwrites dead h1f)
    //   hid    fp32 [16384,256]  @  80  (16)
    char* base = (char*)d_ws;
    _Float16* feats  = (_Float16*)base;
    _Float16* h1f    = (_Float16*)(base + (64ll  << 20));
    _Float16* h1x    = (_Float16*)base;
    float*    h2     = (float*)   (base + (128ll << 20));
    float*    normed = (float*)   (base + (64ll  << 20));
    float*    hid    = (float*)   (base + (80ll  << 20));

    const dim3 blkG(512);
    const dim3 blk(256);

    P4 Xs  = {{d_in[0], d_in[1], d_in[2], d_in[3]}};
    P4 Wms = {{d_in[5], d_in[7], d_in[9], d_in[11]}};
    P4 bms = {{d_in[6], d_in[8], d_in[10], d_in[12]}};
    P4 F4  = {{feats, feats, feats, feats}};
    P4 G1W = {{d_in[13], d_in[13], d_in[13], d_in[13]}};
    P4 H1X = {{h1x, h1x, h1x, h1x}};
    P4 G2W = {{d_in[17], d_in[17], d_in[17], d_in[17]}};
    P4 N4  = {{normed, normed, normed, normed}};
    P4 HW1 = {{d_in[23], d_in[23], d_in[23], d_in[23]}};
    P4 HB1 = {{d_in[24], d_in[24], d_in[24], d_in[24]}};
    P4 NUL = {{nullptr, nullptr, nullptr, nullptr}};

    // 1) projections (z-batched, XCD-swizzled): feats fp16
    gemm_h8<0, true, true, true, true><<<dim3(2, 128, 4), blkG, 0, stream>>>(
        Xs, Wms, bms, feats, /*K=*/1024, /*lda=*/1024, /*ldc=*/1024, /*zofs=*/256);

    // 2) gat1 linear (XCD-swizzled): h1f fp16 = feats(fp16) @ g1_W^T
    gemm_h8<0, false, true, false, true><<<dim3(4, 512, 1), blkG, 0, stream>>>(
        F4, G1W, NUL, h1f, 256, 256, 512, 0);

    // 3) gat1 attention + bias + gelu: h1f fp16 -> h1x fp16
    gat1_attn_kernel<<<dim3(16384), blk, 0, stream>>>(
        h1f, h1x, miss, g1_al, g1_ar, g1_b);

    // 4) gat2 linear (XCD-swizzled): h2 fp32 = h1x(fp16) @ g2_W^T
    gemm_h8<0, false, false, false, true><<<dim3(2, 512, 1), blkG, 0, stream>>>(
        H1X, G2W, NUL, h2, 512, 512, 256, 0);

    // 5) gat2 attention + pool + layernorm -> normed fp32
    gat2_attn_kernel<<<dim3(4096), blk, 0, stream>>>(
        h2, miss, g2_al, g2_ar, g2_b, ln_g, ln_b, normed);

    // 6) head1: hid fp32 = relu(normed @ h_W1^T + h_b1)
    gemm_h8<1, true, false, true, false><<<dim3(2, 128, 1), blkG, 0, stream>>>(
        N4, HW1, HB1, hid, 256, 256, 256, 0);

    // 7) head2: out[16384,8]
    head2_kernel<<<dim3(512), blk, 0, stream>>>(hid, h_W2, h_b2, out);
}

// Round 24
// 323.692 us; speedup vs baseline: 1.4087x; 1.0320x over previous
//
#include <hip/hip_runtime.h>

// B=16384, FEAT=1024, FD=256, M=4 nodes, H1=4x128 (concat->512), H2=1x256, OUT=8.
// Round 24: r23 base (best, 334us) + fp16 h2 (gat2-lin OUT_F16 epilogue;
// gat2_attn reads fp16 — same validated cast class as h1-fp16 which held the
// floor) + fp16 normed (relocated head1-staging cast, bit-identical; head1
// takes the fp16-A path). Saves ~100MB of h2/normed traffic.

typedef __attribute__((ext_vector_type(8))) _Float16 f16x8;
typedef __attribute__((ext_vector_type(4))) float f32x4;

struct P4 { const void* p[4]; };

#define SYM(i,j) ((i)*(7-(i))/2 + (j))

__device__ __forceinline__ float sigmoidf_(float x) { return 1.0f / (1.0f + __expf(-x)); }
__device__ __forceinline__ float gelu_(float x) {
    return 0.5f * x * (1.0f + erff(x * 0.70710678118654752440f));
}

// ---- MFMA NT GEMM, 512 threads = 8 waves (2 row x 4 col), BM=BN=128, BK=32 --
// (r22 verbatim) A fp32 (cvt at ds_write) or fp16 (direct); W fp32 (cvt);
// C fp32 (scattered) or fp16 (LDS-transpose epilogue). SWZ: XCD chunked remap.
template<int ACT, bool A_F32, bool OUT_F16, bool HAS_BIAS, bool SWZ>
__global__ __launch_bounds__(512)
void gemm_h8(P4 A4, P4 W4, P4 b4, void* __restrict__ Cv,
             int K, int lda, int ldc, int zofs)
{
    __shared__ __align__(16) unsigned char smem[32768];
    _Float16 (*As)[128][32] = (_Float16(*)[128][32])smem;            // [2][128][32]
    _Float16 (*Bs)[128][32] = (_Float16(*)[128][32])(smem + 16384);  // [2][128][32]
    _Float16 (*outT)[128]   = (_Float16(*)[128])smem;                // [128][128] alias

    const int z = blockIdx.z;
    const float* __restrict__ bias = (const float*)b4.p[z];
    const float* __restrict__ Bw   = (const float*)W4.p[z];

    int bx = blockIdx.x, by = blockIdx.y;
    if constexpr (SWZ) {
        const int nxy  = gridDim.x * gridDim.y;
        const int flat = by * gridDim.x + bx;
        const int chunk = nxy >> 3;
        const int swz = (flat & 7) * chunk + (flat >> 3);
        bx = swz % gridDim.x;
        by = swz / gridDim.x;
    }

    const int t    = threadIdx.x;
    const int lane = t & 63;
    const int w    = t >> 6;
    const int wr   = (w >> 2) << 6;
    const int wc   = (w & 3) << 5;
    const long rowA = (long)by * 128;
    const long colB = (long)bx * 128;

    const float* Bpt[2];
    int brr[2], bcc[2];
    #pragma unroll
    for (int i = 0; i < 2; ++i) {
        const int f = t + i * 512;
        brr[i] = f >> 3;
        bcc[i] = (f & 7) << 2;
        Bpt[i] = Bw + (colB + brr[i]) * (long)K + bcc[i];
    }
    const float* Apt32[2]; int arr[2], acc_[2];
    const _Float16* Apt16 = nullptr; int a16r = 0, a16c = 0;
    if constexpr (A_F32) {
        const float* A = (const float*)A4.p[z];
        #pragma unroll
        for (int i = 0; i < 2; ++i) {
            const int f = t + i * 512;
            arr[i] = f >> 3;
            acc_[i] = (f & 7) << 2;
            Apt32[i] = A + (rowA + arr[i]) * (long)lda + acc_[i];
        }
    } else {
        const _Float16* A = (const _Float16*)A4.p[z];
        a16r = t >> 2;
        a16c = (t & 3) << 3;
        Apt16 = A + (rowA + a16r) * (long)lda + a16c;
    }

    f32x4 acc[4][2] = {};
    const int NK = K >> 5;

    float4 aP32[2], aN32[2], bP[2], bN[2];
    uint4  aP16 = {}, aN16 = {};

    if constexpr (A_F32) {
        #pragma unroll
        for (int i = 0; i < 2; ++i) aP32[i] = *(const float4*)(Apt32[i]);
    } else {
        aP16 = *(const uint4*)(Apt16);
    }
    #pragma unroll
    for (int i = 0; i < 2; ++i) bP[i] = *(const float4*)(Bpt[i]);

    if constexpr (A_F32) {
        #pragma unroll
        for (int i = 0; i < 2; ++i) {
            union { _Float16 h[4]; uint2 u; } pa;
            pa.h[0] = (_Float16)aP32[i].x; pa.h[1] = (_Float16)aP32[i].y;
            pa.h[2] = (_Float16)aP32[i].z; pa.h[3] = (_Float16)aP32[i].w;
            *(uint2*)&As[0][arr[i]][acc_[i]] = pa.u;
        }
    } else {
        *(uint4*)&As[0][a16r][a16c] = aP16;
    }
    #pragma unroll
    for (int i = 0; i < 2; ++i) {
        union { _Float16 h[4]; uint2 u; } pb;
        pb.h[0] = (_Float16)bP[i].x; pb.h[1] = (_Float16)bP[i].y;
        pb.h[2] = (_Float16)bP[i].z; pb.h[3] = (_Float16)bP[i].w;
        *(uint2*)&Bs[0][brr[i]][bcc[i]] = pb.u;
    }
    if (NK > 1) {
        if constexpr (A_F32) {
            #pragma unroll
            for (int i = 0; i < 2; ++i) aP32[i] = *(const float4*)(Apt32[i] + 32);
        } else {
            aP16 = *(const uint4*)(Apt16 + 32);
        }
        #pragma unroll
        for (int i = 0; i < 2; ++i) bP[i] = *(const float4*)(Bpt[i] + 32);
    }
    __syncthreads();

    const int fr = lane & 15;
    const int fq = lane >> 4;
    const int fg = fq << 3;

    for (int kk = 0; kk < NK; ++kk) {
        const int cur = kk & 1, nxt = cur ^ 1;

        if (kk + 1 < NK) {
            if constexpr (A_F32) {
                #pragma unroll
                for (int i = 0; i < 2; ++i) {
                    union { _Float16 h[4]; uint2 u; } pa;
                    pa.h[0] = (_Float16)aP32[i].x; pa.h[1] = (_Float16)aP32[i].y;
                    pa.h[2] = (_Float16)aP32[i].z; pa.h[3] = (_Float16)aP32[i].w;
                    *(uint2*)&As[nxt][arr[i]][acc_[i]] = pa.u;
                }
            } else {
                *(uint4*)&As[nxt][a16r][a16c] = aP16;
            }
            #pragma unroll
            for (int i = 0; i < 2; ++i) {
                union { _Float16 h[4]; uint2 u; } pb;
                pb.h[0] = (_Float16)bP[i].x; pb.h[1] = (_Float16)bP[i].y;
                pb.h[2] = (_Float16)bP[i].z; pb.h[3] = (_Float16)bP[i].w;
                *(uint2*)&Bs[nxt][brr[i]][bcc[i]] = pb.u;
            }
        }

        if (kk + 2 < NK) {
            const int ko = (kk + 2) << 5;
            if constexpr (A_F32) {
                #pragma unroll
                for (int i = 0; i < 2; ++i) aN32[i] = *(const float4*)(Apt32[i] + ko);
            } else {
                aN16 = *(const uint4*)(Apt16 + ko);
            }
            #pragma unroll
            for (int i = 0; i < 2; ++i) bN[i] = *(const float4*)(Bpt[i] + ko);
        }

        f16x8 af[4], bf[2];
        #pragma unroll
        for (int m = 0; m < 4; ++m) af[m] = *(const f16x8*)&As[cur][wr + m*16 + fr][fg];
        #pragma unroll
        for (int n = 0; n < 2; ++n) bf[n] = *(const f16x8*)&Bs[cur][wc + n*16 + fr][fg];
        #pragma unroll
        for (int m = 0; m < 4; ++m)
            #pragma unroll
            for (int n = 0; n < 2; ++n)
                acc[m][n] = __builtin_amdgcn_mfma_f32_16x16x32_f16(af[m], bf[n], acc[m][n], 0, 0, 0);

        __syncthreads();
        if (kk + 2 < NK) {
            if constexpr (A_F32) {
                #pragma unroll
                for (int i = 0; i < 2; ++i) aP32[i] = aN32[i];
            } else {
                aP16 = aN16;
            }
            #pragma unroll
            for (int i = 0; i < 2; ++i) bP[i] = bN[i];
        }
    }

    if constexpr (OUT_F16) {
        _Float16* Cz = (_Float16*)Cv + (long)z * zofs;
        __syncthreads();
        float bn[2];
        #pragma unroll
        for (int n = 0; n < 2; ++n)
            bn[n] = HAS_BIAS ? bias[colB + wc + n*16 + fr] : 0.0f;
        #pragma unroll
        for (int m = 0; m < 4; ++m)
            #pragma unroll
            for (int n = 0; n < 2; ++n)
                #pragma unroll
                for (int j = 0; j < 4; ++j) {
                    float x = acc[m][n][j] + bn[n];
                    if (ACT == 1) x = fmaxf(x, 0.0f);
                    outT[wr + m*16 + fq*4 + j][wc + n*16 + fr] = (_Float16)x;
                }
        __syncthreads();
        #pragma unroll
        for (int i = 0; i < 4; ++i) {
            const int s = t + i * 512;
            const int r = s >> 4, c = (s & 15) << 3;
            *(uint4*)(Cz + (rowA + r) * (long)ldc + colB + c) = *(const uint4*)&outT[r][c];
        }
    } else {
        float* Cz = (float*)Cv + (long)z * zofs;
        #pragma unroll
        for (int n = 0; n < 2; ++n) {
            const long col = colB + wc + n*16 + fr;
            const float bn = HAS_BIAS ? bias[col] : 0.0f;
            #pragma unroll
            for (int m = 0; m < 4; ++m) {
                const long row0 = rowA + wr + m*16 + fq*4;
                #pragma unroll
                for (int j = 0; j < 4; ++j) {
                    float x = acc[m][n][j] + bn;
                    if (ACT == 1) x = fmaxf(x, 0.0f);
                    Cz[(row0 + j) * (long)ldc + col] = x;
                }
            }
        }
    }
}

// -- GAT1 attention (r23 verbatim): fp16 in, fp32 compute, fp16 out ----------
__global__ __launch_bounds__(256)
void gat1_attn_kernel(const _Float16* __restrict__ h1f,
                      _Float16* __restrict__ h1x,
                      const int* __restrict__ missing,
                      const float* __restrict__ attl, const float* __restrict__ attr,
                      const float* __restrict__ bias)
{
    const int gtid = blockIdx.x * 256 + threadIdx.x;
    const int wid  = gtid >> 6;
    const int lane = threadIdx.x & 63;
    const int b = wid >> 2;
    const int h = wid & 3;
    const int cb = h * 128 + lane;
    const _Float16* bi = h1f + (size_t)b * 2048 + cb;
    _Float16*       bo = h1x + (size_t)b * 2048 + cb;

    float hr[4][2];
    #pragma unroll
    for (int j = 0; j < 4; ++j) {
        hr[j][0] = (float)bi[j*512];
        hr[j][1] = (float)bi[j*512 + 64];
    }
    const float al0 = attl[cb], al1 = attl[cb+64];
    const float ar0 = attr[cb], ar1 = attr[cb+64];

    float red[18];
    #pragma unroll
    for (int i = 0; i < 4; ++i)
        #pragma unroll
        for (int j = i; j < 4; ++j)
            red[SYM(i,j)] = hr[i][0]*hr[j][0] + hr[i][1]*hr[j][1];
    #pragma unroll
    for (int j = 0; j < 4; ++j) {
        red[10+j] = hr[j][0]*al0 + hr[j][1]*al1;
        red[14+j] = hr[j][0]*ar0 + hr[j][1]*ar1;
    }
    #pragma unroll
    for (int m = 1; m < 64; m <<= 1)
        #pragma unroll
        for (int r = 0; r < 18; ++r)
            red[r] += __shfl_xor(red[r], m, 64);

    const int miss = missing[b];
    bool pres[4];
    #pragma unroll
    for (int mm = 0; mm < 4; ++mm) pres[mm] = (miss != mm + 1);

    float attn[4][4];
    #pragma unroll
    for (int i = 0; i < 4; ++i) {
        float av[4]; float mx = -3.4e38f;
        #pragma unroll
        for (int j = 0; j < 4; ++j) {
            const bool mk = (i == j) || (pres[i] && pres[j]);
            const float l = (i <= j) ? red[SYM(i,j)] : red[SYM(j,i)];
            float v = (red[14+i] + red[10+j]) * sigmoidf_(l);
            v = (v >= 0.0f) ? v : 0.2f * v;
            av[j] = mk ? v : -1e30f;
            mx = fmaxf(mx, av[j]);
        }
        float den = 0.0f;
        #pragma unroll
        for (int j = 0; j < 4; ++j) { av[j] = __expf(av[j] - mx); den += av[j]; }
        const float inv = 1.0f / den;
        #pragma unroll
        for (int j = 0; j < 4; ++j) attn[i][j] = av[j] * inv;
    }

    const float b0 = bias[cb], b1 = bias[cb+64];
    #pragma unroll
    for (int i = 0; i < 4; ++i) {
        float o0 = b0, o1 = b1;
        #pragma unroll
        for (int j = 0; j < 4; ++j) { o0 += attn[i][j]*hr[j][0]; o1 += attn[i][j]*hr[j][1]; }
        bo[i*512]      = (_Float16)gelu_(o0);
        bo[i*512 + 64] = (_Float16)gelu_(o1);
    }
}

// ------- GAT2 attention + pool + LayerNorm: fp16 h2 in, fp16 normed out ------
__global__ __launch_bounds__(256)
void gat2_attn_kernel(const _Float16* __restrict__ h2h,
                      const int* __restrict__ missing,
                      const float* __restrict__ attl, const float* __restrict__ attr,
                      const float* __restrict__ bias,
                      const float* __restrict__ lng, const float* __restrict__ lnb,
                      _Float16* __restrict__ normed)
{
    const int gtid = blockIdx.x * 256 + threadIdx.x;
    const int b = gtid >> 6;
    const int lane = threadIdx.x & 63;
    const _Float16* hp = h2h + (size_t)b * 1024;

    float4 hr[4];
    #pragma unroll
    for (int j = 0; j < 4; ++j) {
        union { uint2 u; _Float16 h[4]; } v;
        v.u = *(const uint2*)(hp + j * 256 + lane * 4);
        hr[j].x = (float)v.h[0]; hr[j].y = (float)v.h[1];
        hr[j].z = (float)v.h[2]; hr[j].w = (float)v.h[3];
    }
    const float4 al = ((const float4*)attl)[lane];
    const float4 ar = ((const float4*)attr)[lane];

    float red[18];
    #pragma unroll
    for (int i = 0; i < 4; ++i)
        #pragma unroll
        for (int j = i; j < 4; ++j)
            red[SYM(i,j)] = hr[i].x*hr[j].x + hr[i].y*hr[j].y + hr[i].z*hr[j].z + hr[i].w*hr[j].w;
    #pragma unroll
    for (int j = 0; j < 4; ++j) {
        red[10+j] = hr[j].x*al.x + hr[j].y*al.y + hr[j].z*al.z + hr[j].w*al.w;
        red[14+j] = hr[j].x*ar.x + hr[j].y*ar.y + hr[j].z*ar.z + hr[j].w*ar.w;
    }
    #pragma unroll
    for (int m = 1; m < 64; m <<= 1)
        #pragma unroll
        for (int r = 0; r < 18; ++r)
            red[r] += __shfl_xor(red[r], m, 64);

    const int miss = missing[b];
    bool pres[4];
    #pragma unroll
    for (int mm = 0; mm < 4; ++mm) pres[mm] = (miss != mm + 1);

    float wsum[4] = {0.f, 0.f, 0.f, 0.f};
    #pragma unroll
    for (int i = 0; i < 4; ++i) {
        float av[4]; float mx = -3.4e38f;
        #pragma unroll
        for (int j = 0; j < 4; ++j) {
            const bool mk = (i == j) || (pres[i] && pres[j]);
            const float l = (i <= j) ? red[SYM(i,j)] : red[SYM(j,i)];
            float v = (red[14+i] + red[10+j]) * sigmoidf_(l);
            v = (v >= 0.0f) ? v : 0.2f * v;
            av[j] = mk ? v : -1e30f;
            mx = fmaxf(mx, av[j]);
        }
        float den = 0.0f;
        #pragma unroll
        for (int j = 0; j < 4; ++j) { av[j] = __expf(av[j] - mx); den += av[j]; }
        const float inv = 0.25f / den;
        #pragma unroll
        for (int j = 0; j < 4; ++j) wsum[j] += av[j] * inv;
    }

    const float4 bv = ((const float4*)bias)[lane];
    float pooled[4] = {bv.x, bv.y, bv.z, bv.w};
    #pragma unroll
    for (int j = 0; j < 4; ++j) {
        pooled[0] += wsum[j] * hr[j].x;
        pooled[1] += wsum[j] * hr[j].y;
        pooled[2] += wsum[j] * hr[j].z;
        pooled[3] += wsum[j] * hr[j].w;
    }

    float s1 = pooled[0] + pooled[1] + pooled[2] + pooled[3];
    float s2 = pooled[0]*pooled[0] + pooled[1]*pooled[1] + pooled[2]*pooled[2] + pooled[3]*pooled[3];
    #pragma unroll
    for (int m = 1; m < 64; m <<= 1) {
        s1 += __shfl_xor(s1, m, 64);
        s2 += __shfl_xor(s2, m, 64);
    }
    const float mu   = s1 * (1.0f / 256.0f);
    const float var  = s2 * (1.0f / 256.0f) - mu * mu;
    const float rstd = rsqrtf(var + 1e-5f);
    const float4 g  = ((const float4*)lng)[lane];
    const float4 bb = ((const float4*)lnb)[lane];
    union { _Float16 h[4]; uint2 u; } o;    // cast == head1's staging cast
    o.h[0] = (_Float16)((pooled[0] - mu) * rstd * g.x + bb.x);
    o.h[1] = (_Float16)((pooled[1] - mu) * rstd * g.y + bb.y);
    o.h[2] = (_Float16)((pooled[2] - mu) * rstd * g.z + bb.z);
    o.h[3] = (_Float16)((pooled[3] - mu) * rstd * g.w + bb.w);
    *(uint2*)(normed + (size_t)b * 256 + lane * 4) = o.u;
}

// ---------------- head2 (round-4 verbatim): fp32 hid ------------------------
__global__ __launch_bounds__(256)
void head2_kernel(const float* __restrict__ hid, const float* __restrict__ W2,
                  const float* __restrict__ b2, float* __restrict__ out)
{
    const int t = blockIdx.x * 256 + threadIdx.x;
    const int b = t >> 3, o = t & 7;
    const float4* hp = (const float4*)(hid + (size_t)b * 256);
    const float4* wp = (const float4*)(W2 + o * 256);
    float acc = b2[o];
    #pragma unroll 8
    for (int c = 0; c < 64; ++c) {
        const float4 hv = hp[c], wv = wp[c];
        acc += hv.x*wv.x + hv.y*wv.y + hv.z*wv.z + hv.w*wv.w;
    }
    out[t] = acc;
}

// ---------------- launch ----------------------------------------------------
extern "C" void kernel_launch(void* const* d_in, const int* in_sizes, int n_in,
                              void* d_out, int out_size, void* d_ws, size_t ws_size,
                              hipStream_t stream)
{
    (void)in_sizes; (void)n_in; (void)out_size; (void)ws_size;
    const int*   miss  = (const int*)d_in[4];
    const float* g1_al = (const float*)d_in[14];
    const float* g1_ar = (const float*)d_in[15];
    const float* g1_b  = (const float*)d_in[16];
    const float* g2_al = (const float*)d_in[18];
    const float* g2_ar = (const float*)d_in[19];
    const float* g2_b  = (const float*)d_in[20];
    const float* ln_g  = (const float*)d_in[21];
    const float* ln_b  = (const float*)d_in[22];
    const float* h_W2  = (const float*)d_in[25];
    const float* h_b2  = (const float*)d_in[26];
    float* out = (float*)d_out;

    // workspace (MiB offsets; peak 160 MiB):
    //   feats  fp16 [16384,1024] @   0  (32)  -> dead after gat1-lin
    //   h1f    fp16 [65536,512]  @  64  (64)  -> dead after gat1_attn
    //   h1x    fp16 [65536,512]  @   0  (64)  (overwrites dead feats)
    //   h2h    fp16 [65536,256]  @ 128  (32)
    //   normed fp16 [16384,256]  @  64  (8)   (overwrites dead h1f)
    //   hid    fp32 [16384,256]  @  80  (16)
    char* base = (char*)d_ws;
    _Float16* feats  = (_Float16*)base;
    _Float16* h1f    = (_Float16*)(base + (64ll  << 20));
    _Float16* h1x    = (_Float16*)base;
    _Float16* h2h    = (_Float16*)(base + (128ll << 20));
    _Float16* normed = (_Float16*)(base + (64ll  << 20));
    float*    hid    = (float*)   (base + (80ll  << 20));

    const dim3 blkG(512);
    const dim3 blk(256);

    P4 Xs  = {{d_in[0], d_in[1], d_in[2], d_in[3]}};
    P4 Wms = {{d_in[5], d_in[7], d_in[9], d_in[11]}};
    P4 bms = {{d_in[6], d_in[8], d_in[10], d_in[12]}};
    P4 F4  = {{feats, feats, feats, feats}};
    P4 G1W = {{d_in[13], d_in[13], d_in[13], d_in[13]}};
    P4 H1X = {{h1x, h1x, h1x, h1x}};
    P4 G2W = {{d_in[17], d_in[17], d_in[17], d_in[17]}};
    P4 N4  = {{normed, normed, normed, normed}};
    P4 HW1 = {{d_in[23], d_in[23], d_in[23], d_in[23]}};
    P4 HB1 = {{d_in[24], d_in[24], d_in[24], d_in[24]}};
    P4 NUL = {{nullptr, nullptr, nullptr, nullptr}};

    // 1) projections (z-batched, XCD-swizzled): feats fp16
    gemm_h8<0, true, true, true, true><<<dim3(2, 128, 4), blkG, 0, stream>>>(
        Xs, Wms, bms, feats, /*K=*/1024, /*lda=*/1024, /*ldc=*/1024, /*zofs=*/256);

    // 2) gat1 linear (XCD-swizzled): h1f fp16 = feats(fp16) @ g1_W^T
    gemm_h8<0, false, true, false, true><<<dim3(4, 512, 1), blkG, 0, stream>>>(
        F4, G1W, NUL, h1f, 256, 256, 512, 0);

    // 3) gat1 attention + bias + gelu: h1f fp16 -> h1x fp16
    gat1_attn_kernel<<<dim3(16384), blk, 0, stream>>>(
        h1f, h1x, miss, g1_al, g1_ar, g1_b);

    // 4) gat2 linear (XCD-swizzled): h2h fp16 = h1x(fp16) @ g2_W^T
    gemm_h8<0, false, true, false, true><<<dim3(2, 512, 1), blkG, 0, stream>>>(
        H1X, G2W, NUL, h2h, 512, 512, 256, 0);

    // 5) gat2 attention + pool + layernorm: h2h fp16 -> normed fp16
    gat2_attn_kernel<<<dim3(4096), blk, 0, stream>>>(
        h2h, miss, g2_al, g2_ar, g2_b, ln_g, ln_b, normed);

    // 6) head1: hid fp32 = relu(normed(fp16) @ h_W1^T + h_b1)
    gemm_h8<1, false, false, true, false><<<dim3(2, 128, 1), blkG, 0, stream>>>(
        N4, HW1, HB1, hid, 256, 256, 256, 0);

    // 7) head2: out[16384,8]
    head2_kernel<<<dim3(512), blk, 0, stream>>>(hid, h_W2, h_b2, out);
}